// Round 2
// baseline (487.090 us; speedup 1.0000x reference)
//
#include <hip/hip_runtime.h>
#include <math.h>

// Problem constants
#define NTOT 4096        // H*W = 64*64
#define NBATCH 8
#define CIN 128
#define CK 64
#define CV 64
#define CO 128
#define BN_COUNT 32768.0f // B*H*W

// Workspace layout (float offsets).
#define OFF_YQ    0ul
#define OFF_YK    2097152ul
#define OFF_V     4194304ul
#define OFF_STATS 6291456ul   // [which(2)][sum/sumsq(2)][64]  (atomic-accumulated)
#define OFF_KV    6291712ul   // [8][64][64]                   (atomic-accumulated)
#define OFF_VSUM  6324480ul   // [8][64]                       (atomic-accumulated)
#define OFF_M     6324992ul   // [8][64][128]  (c,o)
#define OFF_D     6390528ul   // [8][128]

// ---------------------------------------------------------------------------
// Kernel 1: LDS-staged 1x1-conv GEMM for q, k (Wk,bk) and v (Wv,bv), with BN
// batch-stats (sum/sumsq, q & k) and vsum (v) fused into the epilogue.
// grid (64 col-chunks, 8 batch, 3 tensors), block 256. Wave w owns
// o = w*16..w*16+15 (wave-uniform -> W reads are s_loads), lane = column.
// LDS staging provides the outstanding-load depth (round-1 lesson: the
// LDS-free variant stalled at 8.5% VALUBusy on global-load latency).
// ---------------------------------------------------------------------------
__global__ __launch_bounds__(256) void gemm3_fused(
    const float* __restrict__ Xq, const float* __restrict__ Xk, const float* __restrict__ Xv,
    const float* __restrict__ Wk, const float* __restrict__ bk,
    const float* __restrict__ Wv, const float* __restrict__ bv,
    float* __restrict__ Yq, float* __restrict__ Yk, float* __restrict__ Vv,
    float* __restrict__ stats, float* __restrict__ vsum)
{
    const int chunk = blockIdx.x;       // 0..63, 64 cols each
    const int b     = blockIdx.y;
    const int which = blockIdx.z;
    const float* X    = (which == 0) ? Xq : (which == 1) ? Xk : Xv;
    const float* W    = (which == 2) ? Wv : Wk;
    const float* bias = (which == 2) ? bv : bk;
    float* Y          = (which == 0) ? Yq : (which == 1) ? Yk : Vv;

    __shared__ float sX[CIN][64];   // 32 KB

    const int t = threadIdx.x;
    const int lane = t & 63;
    const int wu = __builtin_amdgcn_readfirstlane(t >> 6);  // wave id, uniform

    const int n0 = chunk * 64;
    const float* Xb = X + (size_t)b * (CIN * NTOT) + n0;

    // Stage X tile: 128 c x 64 j via float4 -> 2048 float4s, 8 per thread
#pragma unroll
    for (int r = 0; r < 8; ++r) {
        int idx4 = t + r * 256;           // 0..2047
        int c  = idx4 >> 4;               // 0..127
        int j4 = (idx4 & 15) << 2;        // 0..60
        float4 xv = *(const float4*)(Xb + (size_t)c * NTOT + j4);
        *(float4*)&sX[c][j4] = xv;
    }
    __syncthreads();

    const float* Wp = W + (size_t)wu * 16 * CIN;
    float acc[16];
#pragma unroll
    for (int ki = 0; ki < 16; ++ki) acc[ki] = 0.f;

#pragma unroll 8
    for (int c = 0; c < CIN; ++c) {
        float xv = sX[c][lane];
#pragma unroll
        for (int ki = 0; ki < 16; ++ki)
            acc[ki] += xv * Wp[ki * CIN + c];   // wave-uniform -> s_load
    }

    // Epilogue: bias, store, then per-channel (sum, sumsq) partials
    float* Yb = Y + (size_t)b * (CK * NTOT) + n0;
    float sq[16];
#pragma unroll
    for (int ki = 0; ki < 16; ++ki) {
        const int o = wu * 16 + ki;
        float y = acc[ki] + bias[o];
        Yb[(size_t)o * NTOT + lane] = y;
        acc[ki] = y;            // sum partial
        sq[ki]  = y * y;        // sumsq partial
    }

    // Wave reduction across 64 lanes (each wave owns unique channels o)
#pragma unroll
    for (int off = 32; off > 0; off >>= 1) {
#pragma unroll
        for (int ki = 0; ki < 16; ++ki) {
            acc[ki] += __shfl_down(acc[ki], off, 64);
            sq[ki]  += __shfl_down(sq[ki],  off, 64);
        }
    }
    if (lane == 0) {
        if (which < 2) {
#pragma unroll
            for (int ki = 0; ki < 16; ++ki) {
                const int o = wu * 16 + ki;
                atomicAdd(&stats[which * 128 + o],      acc[ki]);
                atomicAdd(&stats[which * 128 + 64 + o], sq[ki]);
            }
        } else {
#pragma unroll
            for (int ki = 0; ki < 16; ++ki)
                atomicAdd(&vsum[b * CV + wu * 16 + ki], acc[ki]);
        }
    }
}

// ---------------------------------------------------------------------------
// Kernel 2: KV[b,c,v] = sum_n kn[b,c,n]*V[b,v,n].
// kn = L2-normalized-over-c BN(Yk); BN scale/shift computed inline from raw
// stats. grid (64 col-chunks, 8 batch), block 256, atomicAdd partials.
// LDS rows padded to 68 floats (17 float4s): keeps &s[c][4j] 16B-aligned for
// ds_read_b128 while rotating bank-quads per row. Inner loop: 4 n-columns per
// iteration, 8 x b128 reads per 64 FMAs (was 32 x b32 per 64 FMAs).
// ---------------------------------------------------------------------------
__global__ __launch_bounds__(256) void kv_kernel(
    const float* __restrict__ Yk, const float* __restrict__ Vv,
    const float* __restrict__ stats, const float* __restrict__ gamma,
    const float* __restrict__ beta, float* __restrict__ KV)
{
    const int chunk = blockIdx.x;       // 0..63, 64 cols
    const int b     = blockIdx.y;
    __shared__ float sk[64][68];
    __shared__ float sv[64][68];
    __shared__ float rn[64];
    __shared__ float sscl[64], sshf[64];

    const int t = threadIdx.x;
    if (t < 64) {
        float S  = stats[128 + t];          // which = 1 (k)
        float SS = stats[192 + t];
        float mean = S * (1.f / BN_COUNT);
        float var  = SS * (1.f / BN_COUNT) - mean * mean;
        float scl  = gamma[t] * rsqrtf(var + 1e-5f);
        sscl[t] = scl;
        sshf[t] = beta[t] - mean * scl;
    }
    __syncthreads();

    const int n0 = chunk * 64;
    const float* Ykb = Yk + (size_t)b * (CK * NTOT) + n0;
    const float* Vb  = Vv + (size_t)b * (CK * NTOT) + n0;

    // Stage: 64 c x 64 j for k (BN applied) and v
#pragma unroll
    for (int r = 0; r < 4; ++r) {
        int idx4 = t + r * 256;           // 0..1023
        int c  = idx4 >> 4;               // 0..63
        int j4 = (idx4 & 15) << 2;        // 0..60
        float4 kf = *(const float4*)(Ykb + (size_t)c * NTOT + j4);
        float4 vf = *(const float4*)(Vb  + (size_t)c * NTOT + j4);
        float scl = sscl[c], sh = sshf[c];
        float4 ks = make_float4(kf.x * scl + sh, kf.y * scl + sh,
                                kf.z * scl + sh, kf.w * scl + sh);
        *(float4*)&sk[c][j4] = ks;
        *(float4*)&sv[c][j4] = vf;
    }
    __syncthreads();

    // Column L2 norms of k (per spatial position)
    if (t < 64) {
        float ssum = 0.f;
#pragma unroll 8
        for (int c = 0; c < 64; ++c) { float x = sk[c][t]; ssum += x * x; }
        rn[t] = 1.f / (sqrtf(ssum) + 1e-7f);
    }
    __syncthreads();
#pragma unroll
    for (int r = 0; r < 16; ++r) {
        int idx = t + r * 256;
        sk[idx >> 6][idx & 63] *= rn[idx & 63];
    }
    __syncthreads();

    // GEMM: acc[c4][v4] over 64 columns, 4 at a time via float4
    const int tc = t >> 4, tv = t & 15;
    float acc[4][4];
#pragma unroll
    for (int i = 0; i < 4; ++i)
#pragma unroll
        for (int k2 = 0; k2 < 4; ++k2) acc[i][k2] = 0.f;

#pragma unroll 2
    for (int jq = 0; jq < 16; ++jq) {
        float4 a4[4], b4[4];
#pragma unroll
        for (int i = 0; i < 4; ++i)  a4[i] = *(const float4*)&sk[tc * 4 + i][jq * 4];
#pragma unroll
        for (int k2 = 0; k2 < 4; ++k2) b4[k2] = *(const float4*)&sv[tv * 4 + k2][jq * 4];
#pragma unroll
        for (int i = 0; i < 4; ++i)
#pragma unroll
            for (int k2 = 0; k2 < 4; ++k2) {
                acc[i][k2] += a4[i].x * b4[k2].x + a4[i].y * b4[k2].y
                            + a4[i].z * b4[k2].z + a4[i].w * b4[k2].w;
            }
    }

    float* KVb = KV + b * (CK * CV);
#pragma unroll
    for (int i = 0; i < 4; ++i)
#pragma unroll
        for (int k2 = 0; k2 < 4; ++k2)
            atomicAdd(&KVb[(tc * 4 + i) * CV + tv * 4 + k2], acc[i][k2]);
}

// ---------------------------------------------------------------------------
// Kernel 3: M[b,c,o] = sum_v KV[b,c,v]*Ww[o,v];  d[b,o] = bw[o] + sum_v Ww[o,v]*vsum[b,v]
// grid 8 (batch), block 256.
// ---------------------------------------------------------------------------
__global__ __launch_bounds__(256) void m_kernel(
    const float* __restrict__ KV, const float* __restrict__ vsum,
    const float* __restrict__ Ww, const float* __restrict__ bw,
    float* __restrict__ M, float* __restrict__ d)
{
    const int b = blockIdx.x;
    __shared__ float sKV[64][65];
    __shared__ float sWw[128][65];
    __shared__ float svs[64];
    const int t = threadIdx.x;

#pragma unroll
    for (int r = 0; r < 16; ++r) {
        int idx = t + r * 256;                       // 0..4095
        sKV[idx >> 6][idx & 63] = KV[b * (CK * CV) + idx];
    }
#pragma unroll
    for (int r = 0; r < 32; ++r) {
        int idx = t + r * 256;                       // 0..8191
        sWw[idx >> 6][idx & 63] = Ww[idx];
    }
    if (t < 64) svs[t] = vsum[b * CV + t];
    __syncthreads();

#pragma unroll
    for (int r = 0; r < 32; ++r) {
        int idx = t + r * 256;
        int c = idx >> 7, o = idx & 127;
        float acc = 0.f;
#pragma unroll 16
        for (int v = 0; v < 64; ++v) acc += sKV[c][v] * sWw[o][v];
        M[(size_t)b * (CK * CO) + idx] = acc;
    }
    if (t < 128) {
        float acc = bw[t];
#pragma unroll 16
        for (int v = 0; v < 64; ++v) acc += sWw[t][v] * svs[v];
        d[b * CO + t] = acc;
    }
}

// ---------------------------------------------------------------------------
// Kernel 4: out[b,o,n] = d[b,o] + sum_c qn[b,c,n] * M[b,c,o]
// qn = L2-normalized-over-c BN(Yq); BN scale/shift computed inline from raw
// stats. grid (64 col-chunks, 8 batch), block 256.
// ---------------------------------------------------------------------------
__global__ __launch_bounds__(256) void out_kernel(
    const float* __restrict__ Yq, const float* __restrict__ stats,
    const float* __restrict__ gamma, const float* __restrict__ beta,
    const float* __restrict__ M, const float* __restrict__ d,
    float* __restrict__ out)
{
    const int chunk = blockIdx.x;
    const int b     = blockIdx.y;
    __shared__ float sM[CK * CO];    // [c][o] flat, 32 KB
    __shared__ float sq[64][68];     // padded, float4-aligned rows
    __shared__ float rn[64];
    __shared__ float sd[CO];
    __shared__ float sscl[64], sshf[64];

    const int t = threadIdx.x;
    const int n0 = chunk * 64;

#pragma unroll
    for (int r = 0; r < 8; ++r) {
        int idx4 = t + r * 256;
        ((float4*)sM)[idx4] = ((const float4*)(M + (size_t)b * (CK * CO)))[idx4];
    }
    if (t < CO) sd[t] = d[b * CO + t];
    if (t < 64) {
        float S  = stats[t];                // which = 0 (q)
        float SS = stats[64 + t];
        float mean = S * (1.f / BN_COUNT);
        float var  = SS * (1.f / BN_COUNT) - mean * mean;
        float scl  = gamma[t] * rsqrtf(var + 1e-5f);
        sscl[t] = scl;
        sshf[t] = beta[t] - mean * scl;
    }
    __syncthreads();   // sscl/sshf ready before sq staging

    const float* Yb = Yq + (size_t)b * (CK * NTOT) + n0;
#pragma unroll
    for (int r = 0; r < 4; ++r) {
        int idx4 = t + r * 256;
        int c  = idx4 >> 4;
        int j4 = (idx4 & 15) << 2;
        float4 xv = *(const float4*)(Yb + (size_t)c * NTOT + j4);
        float scl = sscl[c], sh = sshf[c];
        sq[c][j4 + 0] = xv.x * scl + sh;
        sq[c][j4 + 1] = xv.y * scl + sh;
        sq[c][j4 + 2] = xv.z * scl + sh;
        sq[c][j4 + 3] = xv.w * scl + sh;
    }
    __syncthreads();
    if (t < 64) {
        float ssum = 0.f;
#pragma unroll 8
        for (int c = 0; c < 64; ++c) { float x = sq[c][t]; ssum += x * x; }
        rn[t] = 1.f / (sqrtf(ssum) + 1e-7f);
    }
    __syncthreads();
#pragma unroll
    for (int r = 0; r < 16; ++r) {
        int idx = t + r * 256;
        sq[idx >> 6][idx & 63] *= rn[idx & 63];
    }
    __syncthreads();

    const int j0 = (t & 15) << 2;       // 4 columns
    const int o0 = (t >> 4) << 3;       // 8 out-channels
    float acc[4][8];
#pragma unroll
    for (int jj = 0; jj < 4; ++jj)
#pragma unroll
        for (int oo = 0; oo < 8; ++oo) acc[jj][oo] = sd[o0 + oo];

#pragma unroll 4
    for (int c = 0; c < 64; ++c) {
        float4 qv = *(const float4*)&sq[c][j0];
        float4 m0 = *(const float4*)&sM[c * CO + o0];
        float4 m1 = *(const float4*)&sM[c * CO + o0 + 4];
        float aq[4] = {qv.x, qv.y, qv.z, qv.w};
        float am[8] = {m0.x, m0.y, m0.z, m0.w, m1.x, m1.y, m1.z, m1.w};
#pragma unroll
        for (int jj = 0; jj < 4; ++jj)
#pragma unroll
            for (int oo = 0; oo < 8; ++oo) acc[jj][oo] += aq[jj] * am[oo];
    }

    float* outb = out + (size_t)b * (CO * NTOT) + n0;
#pragma unroll
    for (int oo = 0; oo < 8; ++oo) {
        float4 st = make_float4(acc[0][oo], acc[1][oo], acc[2][oo], acc[3][oo]);
        *(float4*)&outb[(size_t)(o0 + oo) * NTOT + j0] = st;
    }
}

// ---------------------------------------------------------------------------
extern "C" void kernel_launch(void* const* d_in, const int* in_sizes, int n_in,
                              void* d_out, int out_size, void* d_ws, size_t ws_size,
                              hipStream_t stream) {
    (void)in_sizes; (void)n_in; (void)out_size; (void)ws_size;
    const float* q     = (const float*)d_in[0];
    const float* k     = (const float*)d_in[1];
    const float* v     = (const float*)d_in[2];
    const float* Wk    = (const float*)d_in[3];
    const float* bk    = (const float*)d_in[4];
    const float* gamma = (const float*)d_in[5];
    const float* beta  = (const float*)d_in[6];
    const float* Wv    = (const float*)d_in[7];
    const float* bv    = (const float*)d_in[8];
    const float* Ww    = (const float*)d_in[9];
    const float* bw    = (const float*)d_in[10];
    float* out = (float*)d_out;
    float* ws  = (float*)d_ws;

    float* Yq    = ws + OFF_YQ;
    float* Yk    = ws + OFF_YK;
    float* Vv    = ws + OFF_V;
    float* stats = ws + OFF_STATS;
    float* KV    = ws + OFF_KV;
    float* vsum  = ws + OFF_VSUM;
    float* M     = ws + OFF_M;
    float* dd    = ws + OFF_D;

    // zero all atomic-accumulated buffers (stats, KV, vsum are contiguous)
    hipMemsetAsync(stats, 0, (256 + CK * CV * NBATCH + CV * NBATCH) * sizeof(float), stream);

    gemm3_fused<<<dim3(64, NBATCH, 3), 256, 0, stream>>>(
        q, k, v, Wk, bk, Wv, bv, Yq, Yk, Vv, stats, vsum);
    kv_kernel<<<dim3(64, NBATCH), 256, 0, stream>>>(Yk, Vv, stats, gamma, beta, KV);
    m_kernel<<<NBATCH, 256, 0, stream>>>(KV, vsum, Ww, bw, M, dd);
    out_kernel<<<dim3(64, NBATCH), 256, 0, stream>>>(Yq, stats, gamma, beta, M, dd, out);
}

// Round 3
// 254.512 us; speedup vs baseline: 1.9138x; 1.9138x over previous
//
#include <hip/hip_runtime.h>
#include <math.h>

// Problem constants
#define NTOT 4096        // H*W = 64*64
#define NBATCH 8
#define CIN 128
#define CK 64
#define CV 64
#define CO 128
#define BN_COUNT 32768.0f // B*H*W

// Workspace layout (float offsets). Stays under the proven 6,391,808-float cap.
// stats: [b][which][c] sum at *8, sumsq at *8+4  (padded to kill atomic line contention)
// vsum : [b][v] at *8
// KV   : [b][(c*64+v)*2]  (2x padded)
// M,d  : aliased into the YK region (Yk is dead after kv_kernel; m_kernel runs after)
#define OFF_YQ    0ul
#define OFF_YK    2097152ul
#define OFF_V     4194304ul
#define OFF_STATS 6291456ul   // 8*2*64*8 = 8192 floats
#define OFF_VSUM  6299648ul   // 8*64*8   = 4096 floats
#define OFF_KV    6303744ul   // 8*64*64*2 = 65536 floats
#define OFF_M     2097152ul   // = OFF_YK       (64*128*8 = 65536 floats)
#define OFF_D     2162688ul   // = OFF_YK+65536 (8*128 = 1024 floats)

// ---------------------------------------------------------------------------
// Kernel 1: LDS-staged 1x1-conv GEMM (round-0 proven structure) with BN stats
// (sum/sumsq) and vsum fused into the epilogue via PADDED PER-BATCH atomics.
// Round-2 lesson: atomics to 8 shared cache lines serialized the whole grid
// (~33 ns per same-line op x 8192 ops/line = 275 us). Per-(b,which) slots with
// 8x padding cut chains to ~128 ops/line (~4 us, parallel across 16 groups).
// ---------------------------------------------------------------------------
__global__ __launch_bounds__(256) void gemm3_fused(
    const float* __restrict__ Xq, const float* __restrict__ Xk, const float* __restrict__ Xv,
    const float* __restrict__ Wk, const float* __restrict__ bk,
    const float* __restrict__ Wv, const float* __restrict__ bv,
    float* __restrict__ Yq, float* __restrict__ Yk, float* __restrict__ Vv,
    float* __restrict__ stats, float* __restrict__ vsum)
{
    const int chunk = blockIdx.x;       // 0..63, 64 cols each
    const int b     = blockIdx.y;
    const int which = blockIdx.z;
    const float* X    = (which == 0) ? Xq : (which == 1) ? Xk : Xv;
    const float* W    = (which == 2) ? Wv : Wk;
    const float* bias = (which == 2) ? bv : bk;
    float* Y          = (which == 0) ? Yq : (which == 1) ? Yk : Vv;

    __shared__ float sX[CIN][64];   // 32 KB

    const int t = threadIdx.x;
    const int lane = t & 63;
    const int wu = __builtin_amdgcn_readfirstlane(t >> 6);  // wave id, uniform

    const int n0 = chunk * 64;
    const float* Xb = X + (size_t)b * (CIN * NTOT) + n0;

    // Stage X tile: 128 c x 64 j via float4 -> 2048 float4s, 8 per thread
#pragma unroll
    for (int r = 0; r < 8; ++r) {
        int idx4 = t + r * 256;           // 0..2047
        int c  = idx4 >> 4;               // 0..127
        int j4 = (idx4 & 15) << 2;        // 0..60
        float4 xv = *(const float4*)(Xb + (size_t)c * NTOT + j4);
        *(float4*)&sX[c][j4] = xv;
    }
    __syncthreads();

    const float* Wp = W + (size_t)wu * 16 * CIN;
    float acc[16];
#pragma unroll
    for (int ki = 0; ki < 16; ++ki) acc[ki] = 0.f;

#pragma unroll 8
    for (int c = 0; c < CIN; ++c) {
        float xv = sX[c][lane];
#pragma unroll
        for (int ki = 0; ki < 16; ++ki)
            acc[ki] += xv * Wp[ki * CIN + c];   // wave-uniform -> s_load
    }

    // Epilogue: bias, store, then per-channel (sum, sumsq) partials
    float* Yb = Y + (size_t)b * (CK * NTOT) + n0;
    float sq[16];
#pragma unroll
    for (int ki = 0; ki < 16; ++ki) {
        const int o = wu * 16 + ki;
        float y = acc[ki] + bias[o];
        Yb[(size_t)o * NTOT + lane] = y;
        acc[ki] = y;            // sum partial
        sq[ki]  = y * y;        // sumsq partial
    }

    // Wave reduction across 64 lanes (each wave owns unique channels o)
#pragma unroll
    for (int off = 32; off > 0; off >>= 1) {
#pragma unroll
        for (int ki = 0; ki < 16; ++ki) {
            acc[ki] += __shfl_down(acc[ki], off, 64);
            sq[ki]  += __shfl_down(sq[ki],  off, 64);
        }
    }
    if (lane == 0) {
        if (which < 2) {
            float* sb = stats + (size_t)(b * 2 + which) * (64 * 8);
#pragma unroll
            for (int ki = 0; ki < 16; ++ki) {
                const int o = wu * 16 + ki;
                atomicAdd(&sb[o * 8],     acc[ki]);
                atomicAdd(&sb[o * 8 + 4], sq[ki]);
            }
        } else {
            float* vb = vsum + (size_t)b * (64 * 8);
#pragma unroll
            for (int ki = 0; ki < 16; ++ki)
                atomicAdd(&vb[(wu * 16 + ki) * 8], acc[ki]);
        }
    }
}

// ---------------------------------------------------------------------------
// Kernel 2: KV[b,c,v] = sum_n kn[b,c,n]*V[b,v,n].
// kn = L2-normalized-over-c BN(Yk); BN scale/shift from padded per-batch
// stats (summed over the 8 batches inline). grid (64 chunks, 8 batch),
// block 256, atomicAdd partials into 2x-padded KV.
// ---------------------------------------------------------------------------
__global__ __launch_bounds__(256) void kv_kernel(
    const float* __restrict__ Yk, const float* __restrict__ Vv,
    const float* __restrict__ stats, const float* __restrict__ gamma,
    const float* __restrict__ beta, float* __restrict__ KV)
{
    const int chunk = blockIdx.x;       // 0..63, 64 cols
    const int b     = blockIdx.y;
    __shared__ float sk[64][68];
    __shared__ float sv[64][68];
    __shared__ float rn[64];
    __shared__ float sscl[64], sshf[64];

    const int t = threadIdx.x;
    if (t < 64) {
        float S = 0.f, SS = 0.f;
#pragma unroll
        for (int bb = 0; bb < 8; ++bb) {
            const float* sb = stats + (size_t)(bb * 2 + 1) * (64 * 8) + t * 8;
            S  += sb[0];
            SS += sb[4];
        }
        float mean = S * (1.f / BN_COUNT);
        float var  = SS * (1.f / BN_COUNT) - mean * mean;
        float scl  = gamma[t] * rsqrtf(var + 1e-5f);
        sscl[t] = scl;
        sshf[t] = beta[t] - mean * scl;
    }
    __syncthreads();

    const int n0 = chunk * 64;
    const float* Ykb = Yk + (size_t)b * (CK * NTOT) + n0;
    const float* Vb  = Vv + (size_t)b * (CK * NTOT) + n0;

    // Stage: 64 c x 64 j for k (BN applied) and v
#pragma unroll
    for (int r = 0; r < 4; ++r) {
        int idx4 = t + r * 256;           // 0..1023
        int c  = idx4 >> 4;               // 0..63
        int j4 = (idx4 & 15) << 2;        // 0..60
        float4 kf = *(const float4*)(Ykb + (size_t)c * NTOT + j4);
        float4 vf = *(const float4*)(Vb  + (size_t)c * NTOT + j4);
        float scl = sscl[c], sh = sshf[c];
        float4 ks = make_float4(kf.x * scl + sh, kf.y * scl + sh,
                                kf.z * scl + sh, kf.w * scl + sh);
        *(float4*)&sk[c][j4] = ks;
        *(float4*)&sv[c][j4] = vf;
    }
    __syncthreads();

    // Column L2 norms of k (per spatial position)
    if (t < 64) {
        float ssum = 0.f;
#pragma unroll 8
        for (int c = 0; c < 64; ++c) { float x = sk[c][t]; ssum += x * x; }
        rn[t] = 1.f / (sqrtf(ssum) + 1e-7f);
    }
    __syncthreads();
#pragma unroll
    for (int r = 0; r < 16; ++r) {
        int idx = t + r * 256;
        sk[idx >> 6][idx & 63] *= rn[idx & 63];
    }
    __syncthreads();

    // GEMM: acc[c4][v4] over 64 columns, 4 at a time via float4
    const int tc = t >> 4, tv = t & 15;
    float acc[4][4];
#pragma unroll
    for (int i = 0; i < 4; ++i)
#pragma unroll
        for (int k2 = 0; k2 < 4; ++k2) acc[i][k2] = 0.f;

#pragma unroll 2
    for (int jq = 0; jq < 16; ++jq) {
        float4 a4[4], b4[4];
#pragma unroll
        for (int i = 0; i < 4; ++i)  a4[i] = *(const float4*)&sk[tc * 4 + i][jq * 4];
#pragma unroll
        for (int k2 = 0; k2 < 4; ++k2) b4[k2] = *(const float4*)&sv[tv * 4 + k2][jq * 4];
#pragma unroll
        for (int i = 0; i < 4; ++i)
#pragma unroll
            for (int k2 = 0; k2 < 4; ++k2) {
                acc[i][k2] += a4[i].x * b4[k2].x + a4[i].y * b4[k2].y
                            + a4[i].z * b4[k2].z + a4[i].w * b4[k2].w;
            }
    }

    float* KVb = KV + (size_t)b * (CK * CV * 2);
#pragma unroll
    for (int i = 0; i < 4; ++i)
#pragma unroll
        for (int k2 = 0; k2 < 4; ++k2)
            atomicAdd(&KVb[((tc * 4 + i) * CV + tv * 4 + k2) * 2], acc[i][k2]);
}

// ---------------------------------------------------------------------------
// Kernel 3: M[b,c,o] = sum_v KV[b,c,v]*Ww[o,v];  d[b,o] = bw[o] + sum_v Ww[o,v]*vsum[b,v]
// grid 8 (batch), block 256. Reads 2x-padded KV and 8x-padded vsum.
// ---------------------------------------------------------------------------
__global__ __launch_bounds__(256) void m_kernel(
    const float* __restrict__ KV, const float* __restrict__ vsum,
    const float* __restrict__ Ww, const float* __restrict__ bw,
    float* __restrict__ M, float* __restrict__ d)
{
    const int b = blockIdx.x;
    __shared__ float sKV[64][65];
    __shared__ float sWw[128][65];
    __shared__ float svs[64];
    const int t = threadIdx.x;

#pragma unroll
    for (int r = 0; r < 16; ++r) {
        int idx = t + r * 256;                       // 0..4095
        sKV[idx >> 6][idx & 63] = KV[(size_t)b * (CK * CV * 2) + idx * 2];
    }
#pragma unroll
    for (int r = 0; r < 32; ++r) {
        int idx = t + r * 256;                       // 0..8191
        sWw[idx >> 6][idx & 63] = Ww[idx];
    }
    if (t < 64) svs[t] = vsum[(size_t)b * (64 * 8) + t * 8];
    __syncthreads();

#pragma unroll
    for (int r = 0; r < 32; ++r) {
        int idx = t + r * 256;
        int c = idx >> 7, o = idx & 127;
        float acc = 0.f;
#pragma unroll 16
        for (int v = 0; v < 64; ++v) acc += sKV[c][v] * sWw[o][v];
        M[(size_t)b * (CK * CO) + idx] = acc;
    }
    if (t < 128) {
        float acc = bw[t];
#pragma unroll 16
        for (int v = 0; v < 64; ++v) acc += sWw[t][v] * svs[v];
        d[b * CO + t] = acc;
    }
}

// ---------------------------------------------------------------------------
// Kernel 4: out[b,o,n] = d[b,o] + sum_c qn[b,c,n] * M[b,c,o]
// qn = L2-normalized-over-c BN(Yq); BN scale/shift from padded per-batch
// stats. grid (64 col-chunks, 8 batch), block 256.
// ---------------------------------------------------------------------------
__global__ __launch_bounds__(256) void out_kernel(
    const float* __restrict__ Yq, const float* __restrict__ stats,
    const float* __restrict__ gamma, const float* __restrict__ beta,
    const float* __restrict__ M, const float* __restrict__ d,
    float* __restrict__ out)
{
    const int chunk = blockIdx.x;
    const int b     = blockIdx.y;
    __shared__ float sM[CK * CO];    // [c][o] flat, 32 KB
    __shared__ float sq[64][68];     // padded, float4-aligned rows
    __shared__ float rn[64];
    __shared__ float sd[CO];
    __shared__ float sscl[64], sshf[64];

    const int t = threadIdx.x;
    const int n0 = chunk * 64;

#pragma unroll
    for (int r = 0; r < 8; ++r) {
        int idx4 = t + r * 256;
        ((float4*)sM)[idx4] = ((const float4*)(M + (size_t)b * (CK * CO)))[idx4];
    }
    if (t < CO) sd[t] = d[b * CO + t];
    if (t < 64) {
        float S = 0.f, SS = 0.f;
#pragma unroll
        for (int bb = 0; bb < 8; ++bb) {
            const float* sb = stats + (size_t)(bb * 2) * (64 * 8) + t * 8;
            S  += sb[0];
            SS += sb[4];
        }
        float mean = S * (1.f / BN_COUNT);
        float var  = SS * (1.f / BN_COUNT) - mean * mean;
        float scl  = gamma[t] * rsqrtf(var + 1e-5f);
        sscl[t] = scl;
        sshf[t] = beta[t] - mean * scl;
    }
    __syncthreads();   // sscl/sshf ready before sq staging

    const float* Yb = Yq + (size_t)b * (CK * NTOT) + n0;
#pragma unroll
    for (int r = 0; r < 4; ++r) {
        int idx4 = t + r * 256;
        int c  = idx4 >> 4;
        int j4 = (idx4 & 15) << 2;
        float4 xv = *(const float4*)(Yb + (size_t)c * NTOT + j4);
        float scl = sscl[c], sh = sshf[c];
        sq[c][j4 + 0] = xv.x * scl + sh;
        sq[c][j4 + 1] = xv.y * scl + sh;
        sq[c][j4 + 2] = xv.z * scl + sh;
        sq[c][j4 + 3] = xv.w * scl + sh;
    }
    __syncthreads();
    if (t < 64) {
        float ssum = 0.f;
#pragma unroll 8
        for (int c = 0; c < 64; ++c) { float x = sq[c][t]; ssum += x * x; }
        rn[t] = 1.f / (sqrtf(ssum) + 1e-7f);
    }
    __syncthreads();
#pragma unroll
    for (int r = 0; r < 16; ++r) {
        int idx = t + r * 256;
        sq[idx >> 6][idx & 63] *= rn[idx & 63];
    }
    __syncthreads();

    const int j0 = (t & 15) << 2;       // 4 columns
    const int o0 = (t >> 4) << 3;       // 8 out-channels
    float acc[4][8];
#pragma unroll
    for (int jj = 0; jj < 4; ++jj)
#pragma unroll
        for (int oo = 0; oo < 8; ++oo) acc[jj][oo] = sd[o0 + oo];

#pragma unroll 4
    for (int c = 0; c < 64; ++c) {
        float4 qv = *(const float4*)&sq[c][j0];
        float4 m0 = *(const float4*)&sM[c * CO + o0];
        float4 m1 = *(const float4*)&sM[c * CO + o0 + 4];
        float aq[4] = {qv.x, qv.y, qv.z, qv.w};
        float am[8] = {m0.x, m0.y, m0.z, m0.w, m1.x, m1.y, m1.z, m1.w};
#pragma unroll
        for (int jj = 0; jj < 4; ++jj)
#pragma unroll
            for (int oo = 0; oo < 8; ++oo) acc[jj][oo] += aq[jj] * am[oo];
    }

    float* outb = out + (size_t)b * (CO * NTOT) + n0;
#pragma unroll
    for (int oo = 0; oo < 8; ++oo) {
        float4 st = make_float4(acc[0][oo], acc[1][oo], acc[2][oo], acc[3][oo]);
        *(float4*)&outb[(size_t)(o0 + oo) * NTOT + j0] = st;
    }
}

// ---------------------------------------------------------------------------
extern "C" void kernel_launch(void* const* d_in, const int* in_sizes, int n_in,
                              void* d_out, int out_size, void* d_ws, size_t ws_size,
                              hipStream_t stream) {
    (void)in_sizes; (void)n_in; (void)out_size; (void)ws_size;
    const float* q     = (const float*)d_in[0];
    const float* k     = (const float*)d_in[1];
    const float* v     = (const float*)d_in[2];
    const float* Wk    = (const float*)d_in[3];
    const float* bk    = (const float*)d_in[4];
    const float* gamma = (const float*)d_in[5];
    const float* beta  = (const float*)d_in[6];
    const float* Wv    = (const float*)d_in[7];
    const float* bv    = (const float*)d_in[8];
    const float* Ww    = (const float*)d_in[9];
    const float* bw    = (const float*)d_in[10];
    float* out = (float*)d_out;
    float* ws  = (float*)d_ws;

    float* Yq    = ws + OFF_YQ;
    float* Yk    = ws + OFF_YK;
    float* Vv    = ws + OFF_V;
    float* stats = ws + OFF_STATS;
    float* vsum  = ws + OFF_VSUM;
    float* KV    = ws + OFF_KV;
    float* M     = ws + OFF_M;    // aliases dead Yk region (safe: stream-ordered)
    float* dd    = ws + OFF_D;    // aliases dead Yk region

    // zero all atomic-accumulated buffers (stats, vsum, KV are contiguous)
    hipMemsetAsync(stats, 0, (8192 + 4096 + 65536) * sizeof(float), stream);

    gemm3_fused<<<dim3(64, NBATCH, 3), 256, 0, stream>>>(
        q, k, v, Wk, bk, Wv, bv, Yq, Yk, Vv, stats, vsum);
    kv_kernel<<<dim3(64, NBATCH), 256, 0, stream>>>(Yk, Vv, stats, gamma, beta, KV);
    m_kernel<<<NBATCH, 256, 0, stream>>>(KV, vsum, Ww, bw, M, dd);
    out_kernel<<<dim3(64, NBATCH), 256, 0, stream>>>(Yq, stats, gamma, beta, M, dd, out);
}

// Round 5
// 203.299 us; speedup vs baseline: 2.3959x; 1.2519x over previous
//
#include <hip/hip_runtime.h>
#include <math.h>

// Problem constants
#define NTOT 4096        // H*W = 64*64
#define NBATCH 8
#define CIN 128
#define CK 64
#define CV 64
#define CO 128
#define BN_COUNT 32768.0f // B*H*W

// Workspace layout (float offsets). Total used = 6,316,032 < proven 6,391,808 cap.
// stats: [(b*2+which)*64 + o]*16  (line-exclusive per channel; sum@+0, sumsq@+4)
// vsum : [(b*64+v)*16]            (line-exclusive per channel)
// Mp,dp: aliased into dead Yk region (Yk last read by kv_kernel; m_kernel after)
// KVp  : 64-chunk partials of KV live in d_out scratch (overwritten by out_kernel)
#define OFF_YQ    0ul
#define OFF_YK    2097152ul
#define OFF_V     4194304ul
#define OFF_STATS 6291456ul           // 16*1024 = 16384 floats
#define OFF_VSUM  6307840ul           // 8*1024  = 8192 floats
#define OFF_MP    2097152ul           // = OFF_YK, [b][half][64][128] = 131072 floats
#define OFF_DP    2228224ul           // [b][half][128] = 2048 floats

// ---------------------------------------------------------------------------
// Kernel 1: LDS-staged 1x1-conv GEMM, 128 cols per block (2 cols/lane) so each
// wave-uniform weight s_load feeds 32 FMAs. BN stats (sum/sumsq) and vsum
// fused in epilogue with LINE-EXCLUSIVE padded atomics (64 ops/line ~ 2us).
// grid (32 col-chunks of 128, 8 batch, 3 tensors), block 256.
// ---------------------------------------------------------------------------
__global__ __launch_bounds__(256) void gemm3_fused(
    const float* __restrict__ Xq, const float* __restrict__ Xk, const float* __restrict__ Xv,
    const float* __restrict__ Wk, const float* __restrict__ bk,
    const float* __restrict__ Wv, const float* __restrict__ bv,
    float* __restrict__ Yq, float* __restrict__ Yk, float* __restrict__ Vv,
    float* __restrict__ stats, float* __restrict__ vsum)
{
    const int chunk = blockIdx.x;       // 0..31, 128 cols each
    const int b     = blockIdx.y;
    const int which = blockIdx.z;
    const float* X    = (which == 0) ? Xq : (which == 1) ? Xk : Xv;
    const float* W    = (which == 2) ? Wv : Wk;
    const float* bias = (which == 2) ? bv : bk;
    float* Y          = (which == 0) ? Yq : (which == 1) ? Yk : Vv;

    __shared__ float sX[CIN][128];   // 64 KB

    const int t = threadIdx.x;
    const int lane = t & 63;
    const int wu = __builtin_amdgcn_readfirstlane(t >> 6);  // wave id, uniform

    const int n0 = chunk * 128;
    const float* Xb = X + (size_t)b * (CIN * NTOT) + n0;

    // Stage X tile: 128 c x 128 j via float4 -> 4096 float4s, 16 per thread
#pragma unroll
    for (int r = 0; r < 16; ++r) {
        int idx4 = t + r * 256;           // 0..4095
        int c  = idx4 >> 5;               // 0..127
        int j4 = (idx4 & 31) << 2;        // 0..124
        float4 xv = *(const float4*)(Xb + (size_t)c * NTOT + j4);
        *(float4*)&sX[c][j4] = xv;
    }
    __syncthreads();

    const float* Wp = W + (size_t)wu * 16 * CIN;
    float a0[16], a1[16];
#pragma unroll
    for (int ki = 0; ki < 16; ++ki) { a0[ki] = 0.f; a1[ki] = 0.f; }

#pragma unroll 8
    for (int c = 0; c < CIN; ++c) {
        float x0 = sX[c][lane];
        float x1 = sX[c][lane + 64];
#pragma unroll
        for (int ki = 0; ki < 16; ++ki) {
            float w = Wp[ki * CIN + c];   // wave-uniform -> s_load, feeds 32 FMAs
            a0[ki] += x0 * w;
            a1[ki] += x1 * w;
        }
    }

    // Epilogue: bias, store both columns, then (sum, sumsq) partials
    float* Yb = Y + (size_t)b * (CK * NTOT) + n0;
#pragma unroll
    for (int ki = 0; ki < 16; ++ki) {
        const int o = wu * 16 + ki;
        const float bo = bias[o];
        float y0 = a0[ki] + bo;
        float y1 = a1[ki] + bo;
        Yb[(size_t)o * NTOT + lane]      = y0;
        Yb[(size_t)o * NTOT + lane + 64] = y1;
        a0[ki] = y0 + y1;                 // sum partial
        a1[ki] = y0 * y0 + y1 * y1;       // sumsq partial
    }

    // Wave reduction across 64 lanes (each wave owns unique channels o)
#pragma unroll
    for (int off = 32; off > 0; off >>= 1) {
#pragma unroll
        for (int ki = 0; ki < 16; ++ki) {
            a0[ki] += __shfl_down(a0[ki], off, 64);
            a1[ki] += __shfl_down(a1[ki], off, 64);
        }
    }
    if (lane == 0) {
        if (which < 2) {
            float* sb = stats + (size_t)(b * 2 + which) * 1024;
#pragma unroll
            for (int ki = 0; ki < 16; ++ki) {
                const int o = wu * 16 + ki;
                atomicAdd(&sb[o * 16],     a0[ki]);
                atomicAdd(&sb[o * 16 + 4], a1[ki]);
            }
        } else {
            float* vb = vsum + (size_t)b * 1024;
#pragma unroll
            for (int ki = 0; ki < 16; ++ki)
                atomicAdd(&vb[(wu * 16 + ki) * 16], a0[ki]);
        }
    }
}

// ---------------------------------------------------------------------------
// Kernel 2: KV partials, ATOMIC-FREE. Each (chunk,b) block computes its
// 64x64 contribution KVp[b][chunk][c][v] and writes it deterministically
// (coalesced float4) into d_out used as scratch (8.4 MB of 16.7 MB; out_kernel
// overwrites all of d_out later). kn = L2-normalized-over-c BN(Yk).
// grid (64 chunks, 8 batch), block 256.
// ---------------------------------------------------------------------------
__global__ __launch_bounds__(256) void kv_kernel(
    const float* __restrict__ Yk, const float* __restrict__ Vv,
    const float* __restrict__ stats, const float* __restrict__ gamma,
    const float* __restrict__ beta, float* __restrict__ KVp)
{
    const int chunk = blockIdx.x;       // 0..63, 64 cols
    const int b     = blockIdx.y;
    __shared__ float sk[64][68];
    __shared__ float sv[64][68];
    __shared__ float rn[64];
    __shared__ float sscl[64], sshf[64];

    const int t = threadIdx.x;
    if (t < 64) {
        float S = 0.f, SS = 0.f;
#pragma unroll
        for (int bb = 0; bb < 8; ++bb) {
            const float* sb = stats + (size_t)(bb * 2 + 1) * 1024 + t * 16;
            S  += sb[0];
            SS += sb[4];
        }
        float mean = S * (1.f / BN_COUNT);
        float var  = SS * (1.f / BN_COUNT) - mean * mean;
        float scl  = gamma[t] * rsqrtf(var + 1e-5f);
        sscl[t] = scl;
        sshf[t] = beta[t] - mean * scl;
    }
    __syncthreads();

    const int n0 = chunk * 64;
    const float* Ykb = Yk + (size_t)b * (CK * NTOT) + n0;
    const float* Vb  = Vv + (size_t)b * (CK * NTOT) + n0;

    // Stage: 64 c x 64 j for k (BN applied) and v
#pragma unroll
    for (int r = 0; r < 4; ++r) {
        int idx4 = t + r * 256;           // 0..1023
        int c  = idx4 >> 4;               // 0..63
        int j4 = (idx4 & 15) << 2;        // 0..60
        float4 kf = *(const float4*)(Ykb + (size_t)c * NTOT + j4);
        float4 vf = *(const float4*)(Vb  + (size_t)c * NTOT + j4);
        float scl = sscl[c], sh = sshf[c];
        float4 ks = make_float4(kf.x * scl + sh, kf.y * scl + sh,
                                kf.z * scl + sh, kf.w * scl + sh);
        *(float4*)&sk[c][j4] = ks;
        *(float4*)&sv[c][j4] = vf;
    }
    __syncthreads();

    // Column L2 norms of k (per spatial position)
    if (t < 64) {
        float ssum = 0.f;
#pragma unroll 8
        for (int c = 0; c < 64; ++c) { float x = sk[c][t]; ssum += x * x; }
        rn[t] = 1.f / (sqrtf(ssum) + 1e-7f);
    }
    __syncthreads();
#pragma unroll
    for (int r = 0; r < 16; ++r) {
        int idx = t + r * 256;
        sk[idx >> 6][idx & 63] *= rn[idx & 63];
    }
    __syncthreads();

    // GEMM: acc[c4][v4] over 64 columns, 4 at a time via float4
    const int tc = t >> 4, tv = t & 15;
    float acc[4][4];
#pragma unroll
    for (int i = 0; i < 4; ++i)
#pragma unroll
        for (int k2 = 0; k2 < 4; ++k2) acc[i][k2] = 0.f;

#pragma unroll 2
    for (int jq = 0; jq < 16; ++jq) {
        float4 a4[4], b4[4];
#pragma unroll
        for (int i = 0; i < 4; ++i)  a4[i] = *(const float4*)&sk[tc * 4 + i][jq * 4];
#pragma unroll
        for (int k2 = 0; k2 < 4; ++k2) b4[k2] = *(const float4*)&sv[tv * 4 + k2][jq * 4];
#pragma unroll
        for (int i = 0; i < 4; ++i)
#pragma unroll
            for (int k2 = 0; k2 < 4; ++k2) {
                acc[i][k2] += a4[i].x * b4[k2].x + a4[i].y * b4[k2].y
                            + a4[i].z * b4[k2].z + a4[i].w * b4[k2].w;
            }
    }

    // Deterministic, coalesced partial store: KVp[b][chunk][c][v]
    float* P = KVp + ((size_t)(b * 64 + chunk)) * 4096;
#pragma unroll
    for (int i = 0; i < 4; ++i) {
        float4 st = make_float4(acc[i][0], acc[i][1], acc[i][2], acc[i][3]);
        *(float4*)&P[(tc * 4 + i) * 64 + tv * 4] = st;
    }
}

// ---------------------------------------------------------------------------
// Kernel 3: reduce KVp over 64 chunks (v-half per block) + partial GEMM:
// Mp[b][half][c][o] = sum_{v in half} KV[b,c,v]*Ww[o,v]
// dp[b][half][o]    = (half==0 ? bw[o] : 0) + sum_{v in half} Ww[o,v]*vsum[b,v]
// grid (2 halves, 8 batch), block 256.
// ---------------------------------------------------------------------------
__global__ __launch_bounds__(256) void m_kernel(
    const float* __restrict__ KVp, const float* __restrict__ vsum,
    const float* __restrict__ Ww, const float* __restrict__ bw,
    float* __restrict__ Mp, float* __restrict__ dp)
{
    const int half = blockIdx.x;        // 0..1 (v range half*32..+32)
    const int b    = blockIdx.y;
    __shared__ float sKV[64][36];       // [c][v-in-half]
    __shared__ float sWw[128][36];      // [o][v-in-half]
    __shared__ float svs[32];
    const int t = threadIdx.x;

    // Stage Ww half: 128 o x 32 v = 1024 float4s
#pragma unroll
    for (int r = 0; r < 4; ++r) {
        int idx4 = t + r * 256;          // 0..1023
        int o  = idx4 >> 3;              // 0..127
        int v4 = (idx4 & 7) << 2;        // 0..28
        *(float4*)&sWw[o][v4] = *(const float4*)(Ww + (size_t)o * 64 + half * 32 + v4);
    }
    if (t < 32) svs[t] = vsum[((size_t)b * 64 + half * 32 + t) * 16];

    // Reduce KVp over 64 chunks: this block covers 64 c x 32 v = 512 float4s,
    // 2 per thread (c and c+32), coalesced within each chunk.
    const float* base = KVp + (size_t)b * 64 * 4096;
    const int c0  = t >> 3;              // 0..31
    const int vq0 = (t & 7) << 2;        // 0..28
    const size_t off0 = (size_t)c0 * 64 + half * 32 + vq0;
    const size_t off1 = (size_t)(c0 + 32) * 64 + half * 32 + vq0;
    float4 r0 = make_float4(0.f, 0.f, 0.f, 0.f);
    float4 r1 = make_float4(0.f, 0.f, 0.f, 0.f);
#pragma unroll 4
    for (int ch = 0; ch < 64; ++ch) {
        const float* pc = base + (size_t)ch * 4096;
        float4 x0 = *(const float4*)(pc + off0);
        float4 x1 = *(const float4*)(pc + off1);
        r0.x += x0.x; r0.y += x0.y; r0.z += x0.z; r0.w += x0.w;
        r1.x += x1.x; r1.y += x1.y; r1.z += x1.z; r1.w += x1.w;
    }
    *(float4*)&sKV[c0][vq0]      = r0;
    *(float4*)&sKV[c0 + 32][vq0] = r1;
    __syncthreads();

    // Partial M: thread owns c = t&63, o group = (t>>6)*32..+32
    const int c  = t & 63;
    const int og = (t >> 6) * 32;
    float kreg[32];
#pragma unroll
    for (int vq = 0; vq < 8; ++vq) {
        float4 kv4 = *(const float4*)&sKV[c][vq * 4];
        kreg[vq * 4 + 0] = kv4.x; kreg[vq * 4 + 1] = kv4.y;
        kreg[vq * 4 + 2] = kv4.z; kreg[vq * 4 + 3] = kv4.w;
    }
    float* Mpb = Mp + ((size_t)b * 2 + half) * 8192;
#pragma unroll
    for (int oi = 0; oi < 32; ++oi) {
        const int o = og + oi;
        float acc = 0.f;
#pragma unroll
        for (int vq = 0; vq < 8; ++vq) {
            float4 w4 = *(const float4*)&sWw[o][vq * 4];
            acc += kreg[vq * 4 + 0] * w4.x + kreg[vq * 4 + 1] * w4.y
                 + kreg[vq * 4 + 2] * w4.z + kreg[vq * 4 + 3] * w4.w;
        }
        Mpb[(size_t)c * CO + o] = acc;
    }

    // Partial d
    if (t < 128) {
        float acc = (half == 0) ? bw[t] : 0.f;
#pragma unroll 8
        for (int v = 0; v < 32; ++v) acc += sWw[t][v] * svs[v];
        dp[((size_t)b * 2 + half) * 128 + t] = acc;
    }
}

// ---------------------------------------------------------------------------
// Kernel 4: out[b,o,n] = d[b,o] + rn[n] * sum_c sq[b,c,n] * M[b,c,o]
// (rn factored OUT of the GEMM -- removes the LDS rescale pass + a barrier).
// sM = Mp0+Mp1, sd = dp0+dp1. grid (64 col-chunks, 8 batch), block 256.
// ---------------------------------------------------------------------------
__global__ __launch_bounds__(256) void out_kernel(
    const float* __restrict__ Yq, const float* __restrict__ stats,
    const float* __restrict__ gamma, const float* __restrict__ beta,
    const float* __restrict__ Mp, const float* __restrict__ dp,
    float* __restrict__ out)
{
    const int chunk = blockIdx.x;
    const int b     = blockIdx.y;
    __shared__ float sM[CK * CO];    // [c][o] flat, 32 KB
    __shared__ float sq[64][68];     // padded, float4-aligned rows
    __shared__ float rn[64];
    __shared__ float sd[CO];
    __shared__ float sscl[64], sshf[64];

    const int t = threadIdx.x;
    const int n0 = chunk * 64;

    const float* Mp0 = Mp + (size_t)b * 2 * 8192;
    const float* Mp1 = Mp0 + 8192;
#pragma unroll
    for (int r = 0; r < 8; ++r) {
        int idx4 = t + r * 256;
        float4 m0 = ((const float4*)Mp0)[idx4];
        float4 m1 = ((const float4*)Mp1)[idx4];
        ((float4*)sM)[idx4] = make_float4(m0.x + m1.x, m0.y + m1.y,
                                          m0.z + m1.z, m0.w + m1.w);
    }
    if (t < CO) sd[t] = dp[(size_t)b * 2 * 128 + t] + dp[((size_t)b * 2 + 1) * 128 + t];
    if (t < 64) {
        float S = 0.f, SS = 0.f;
#pragma unroll
        for (int bb = 0; bb < 8; ++bb) {
            const float* sb = stats + (size_t)(bb * 2) * 1024 + t * 16;
            S  += sb[0];
            SS += sb[4];
        }
        float mean = S * (1.f / BN_COUNT);
        float var  = SS * (1.f / BN_COUNT) - mean * mean;
        float scl  = gamma[t] * rsqrtf(var + 1e-5f);
        sscl[t] = scl;
        sshf[t] = beta[t] - mean * scl;
    }
    __syncthreads();   // sscl/sshf ready before sq staging

    const float* Yb = Yq + (size_t)b * (CK * NTOT) + n0;
#pragma unroll
    for (int r = 0; r < 4; ++r) {
        int idx4 = t + r * 256;
        int c  = idx4 >> 4;
        int j4 = (idx4 & 15) << 2;
        float4 xv = *(const float4*)(Yb + (size_t)c * NTOT + j4);
        float scl = sscl[c], sh = sshf[c];
        sq[c][j4 + 0] = xv.x * scl + sh;
        sq[c][j4 + 1] = xv.y * scl + sh;
        sq[c][j4 + 2] = xv.z * scl + sh;
        sq[c][j4 + 3] = xv.w * scl + sh;
    }
    __syncthreads();
    if (t < 64) {
        float ssum = 0.f;
#pragma unroll 8
        for (int c = 0; c < 64; ++c) { float x = sq[c][t]; ssum += x * x; }
        rn[t] = 1.f / (sqrtf(ssum) + 1e-7f);
    }
    __syncthreads();

    const int j0 = (t & 15) << 2;       // 4 columns
    const int o0 = (t >> 4) << 3;       // 8 out-channels
    float acc[4][8];
#pragma unroll
    for (int jj = 0; jj < 4; ++jj)
#pragma unroll
        for (int oo = 0; oo < 8; ++oo) acc[jj][oo] = 0.f;

#pragma unroll 4
    for (int c = 0; c < 64; ++c) {
        float4 qv = *(const float4*)&sq[c][j0];
        float4 m0 = *(const float4*)&sM[c * CO + o0];
        float4 m1 = *(const float4*)&sM[c * CO + o0 + 4];
        float aq[4] = {qv.x, qv.y, qv.z, qv.w};
        float am[8] = {m0.x, m0.y, m0.z, m0.w, m1.x, m1.y, m1.z, m1.w};
#pragma unroll
        for (int jj = 0; jj < 4; ++jj)
#pragma unroll
            for (int oo = 0; oo < 8; ++oo) acc[jj][oo] += aq[jj] * am[oo];
    }

    float4 rq = *(const float4*)&rn[j0];   // per-thread column norms
    float rnj[4] = {rq.x, rq.y, rq.z, rq.w};

    float* outb = out + (size_t)b * (CO * NTOT) + n0;
#pragma unroll
    for (int oo = 0; oo < 8; ++oo) {
        float dd = sd[o0 + oo];
        float4 st = make_float4(acc[0][oo] * rnj[0] + dd,
                                acc[1][oo] * rnj[1] + dd,
                                acc[2][oo] * rnj[2] + dd,
                                acc[3][oo] * rnj[3] + dd);
        *(float4*)&outb[(size_t)(o0 + oo) * NTOT + j0] = st;
    }
}

// ---------------------------------------------------------------------------
extern "C" void kernel_launch(void* const* d_in, const int* in_sizes, int n_in,
                              void* d_out, int out_size, void* d_ws, size_t ws_size,
                              hipStream_t stream) {
    (void)in_sizes; (void)n_in; (void)out_size; (void)ws_size;
    const float* q     = (const float*)d_in[0];
    const float* k     = (const float*)d_in[1];
    const float* v     = (const float*)d_in[2];
    const float* Wk    = (const float*)d_in[3];
    const float* bk    = (const float*)d_in[4];
    const float* gamma = (const float*)d_in[5];
    const float* beta  = (const float*)d_in[6];
    const float* Wv    = (const float*)d_in[7];
    const float* bv    = (const float*)d_in[8];
    const float* Ww    = (const float*)d_in[9];
    const float* bw    = (const float*)d_in[10];
    float* out = (float*)d_out;
    float* ws  = (float*)d_ws;

    float* Yq    = ws + OFF_YQ;
    float* Yk    = ws + OFF_YK;
    float* Vv    = ws + OFF_V;
    float* stats = ws + OFF_STATS;
    float* vsum  = ws + OFF_VSUM;
    float* Mp    = ws + OFF_MP;    // aliases dead Yk region (stream-ordered safe)
    float* dp    = ws + OFF_DP;    // aliases dead Yk region
    float* KVp   = out;            // d_out as scratch; fully overwritten by out_kernel

    // zero atomic-accumulated buffers (stats + vsum contiguous, 96 KB)
    hipMemsetAsync(stats, 0, (16384 + 8192) * sizeof(float), stream);

    gemm3_fused<<<dim3(32, NBATCH, 3), 256, 0, stream>>>(
        q, k, v, Wk, bk, Wv, bv, Yq, Yk, Vv, stats, vsum);
    kv_kernel<<<dim3(64, NBATCH), 256, 0, stream>>>(Yk, Vv, stats, gamma, beta, KVp);
    m_kernel<<<dim3(2, NBATCH), 256, 0, stream>>>(KVp, vsum, Ww, bw, Mp, dp);
    out_kernel<<<dim3(64, NBATCH), 256, 0, stream>>>(Yq, stats, gamma, beta, Mp, dp, out);
}

// Round 6
// 189.307 us; speedup vs baseline: 2.5730x; 1.0739x over previous
//
#include <hip/hip_runtime.h>
#include <math.h>

// Problem constants
#define NTOT 4096        // H*W = 64*64
#define NBATCH 8
#define CIN 128
#define CK 64
#define CV 64
#define CO 128
#define BN_COUNT 32768.0f // B*H*W

// Workspace layout (float offsets).
// stats: [(which*64+c)*16] sum, +4 sumsq  (global over b,n; line-exclusive/channel)
// vsum : [(b*64+v)*16]                    (line-exclusive per (b,v))
// Mp,dp: aliased into dead Yk region (Yk last read by kv_kernel; m_kernel after)
// KVp  : 64-chunk partials of KV in d_out scratch (overwritten by out_kernel)
#define OFF_YQ    0ul
#define OFF_YK    2097152ul
#define OFF_V     4194304ul
#define OFF_STATS 6291456ul           // 2*64*16 = 2048 floats
#define OFF_VSUM  6293504ul           // 8*64*16 = 8192 floats
#define OFF_MP    2097152ul           // = OFF_YK, [b][half][64][128] = 131072 floats
#define OFF_DP    2228224ul           // [b][half][128] = 2048 floats

// ---------------------------------------------------------------------------
// Kernel 1: LDS-staged 1x1-conv GEMM (round-0 proven: 57us, VALU 37%).
// NO epilogue fusion: rounds 3/5 showed the fused stats epilogue costs ~21us
// regardless of atomic padding (shuffle butterfly + atomic drain).
// grid (64 col-chunks, 8 batch, 3 tensors), block 256.
// ---------------------------------------------------------------------------
__global__ __launch_bounds__(256) void gemm3_kernel(
    const float* __restrict__ Xq, const float* __restrict__ Xk, const float* __restrict__ Xv,
    const float* __restrict__ Wk, const float* __restrict__ bk,
    const float* __restrict__ Wv, const float* __restrict__ bv,
    float* __restrict__ Yq, float* __restrict__ Yk, float* __restrict__ Vv)
{
    const int chunk = blockIdx.x;
    const int b     = blockIdx.y;
    const int which = blockIdx.z;
    const float* X    = (which == 0) ? Xq : (which == 1) ? Xk : Xv;
    const float* W    = (which == 2) ? Wv : Wk;
    const float* bias = (which == 2) ? bv : bk;
    float* Y          = (which == 0) ? Yq : (which == 1) ? Yk : Vv;

    __shared__ float sX[CIN][64];   // 32 KB

    const int t = threadIdx.x;
    const int lane = t & 63;
    const int wu = __builtin_amdgcn_readfirstlane(t >> 6);  // wave id, uniform

    const int n0 = chunk * 64;
    const float* Xb = X + (size_t)b * (CIN * NTOT) + n0;

    // Stage X tile: 128 c x 64 j via float4 -> 2048 float4s, 8 per thread
#pragma unroll
    for (int r = 0; r < 8; ++r) {
        int idx4 = t + r * 256;           // 0..2047
        int c  = idx4 >> 4;               // 0..127
        int j4 = (idx4 & 15) << 2;        // 0..60
        float4 xv = *(const float4*)(Xb + (size_t)c * NTOT + j4);
        *(float4*)&sX[c][j4] = xv;
    }
    __syncthreads();

    const float* Wp = W + (size_t)wu * 16 * CIN;
    float acc[16];
#pragma unroll
    for (int ki = 0; ki < 16; ++ki) acc[ki] = 0.f;

#pragma unroll 8
    for (int c = 0; c < CIN; ++c) {
        float xv = sX[c][lane];
#pragma unroll
        for (int ki = 0; ki < 16; ++ki)
            acc[ki] += xv * Wp[ki * CIN + c];   // wave-uniform -> s_load
    }

    float* Yb = Y + (size_t)b * (CK * NTOT) + n0;
#pragma unroll
    for (int ki = 0; ki < 16; ++ki) {
        int o = wu * 16 + ki;
        Yb[(size_t)o * NTOT + lane] = acc[ki] + bias[o];
    }
}

// ---------------------------------------------------------------------------
// Kernel 2: BN batch stats, dedicated and parallel. grid (8 n-splits, 64 c,
// 2 tensors) = 1024 blocks; each block reads 16KB coalesced (8 batches x 512
// floats of one channel), block-reduces, 2 padded atomics (16 ops/line).
// ---------------------------------------------------------------------------
__global__ __launch_bounds__(256) void stats_kernel(
    const float* __restrict__ Yq, const float* __restrict__ Yk,
    float* __restrict__ stats)
{
    const int nsplit = blockIdx.x;   // 0..7
    const int c      = blockIdx.y;   // 0..63
    const int which  = blockIdx.z;   // 0..1
    const float* Y = which ? Yk : Yq;
    const int t = threadIdx.x;

    float s = 0.f, ss = 0.f;
#pragma unroll
    for (int p = 0; p < 4; ++p) {
        int b = (t >> 7) + p * 2;        // 2 batches per pass
        int e = (t & 127) << 2;          // 0..508
        const float* src = Y + (size_t)b * (CK * NTOT) + (size_t)c * NTOT
                         + nsplit * 512 + e;
        float4 v = *(const float4*)src;
        s  += v.x + v.y + v.z + v.w;
        ss += v.x * v.x + v.y * v.y + v.z * v.z + v.w * v.w;
    }
#pragma unroll
    for (int off = 32; off > 0; off >>= 1) {
        s  += __shfl_down(s, off, 64);
        ss += __shfl_down(ss, off, 64);
    }
    __shared__ float red[8];
    int wave = t >> 6, lane = t & 63;
    if (lane == 0) { red[wave * 2] = s; red[wave * 2 + 1] = ss; }
    __syncthreads();
    if (t == 0) {
        float S  = red[0] + red[2] + red[4] + red[6];
        float SS = red[1] + red[3] + red[5] + red[7];
        atomicAdd(&stats[(which * 64 + c) * 16],     S);
        atomicAdd(&stats[(which * 64 + c) * 16 + 4], SS);
    }
}

// ---------------------------------------------------------------------------
// Kernel 3: KV partials (atomic-free, into d_out scratch) + vsum (padded
// atomics). kn = L2-normalized-over-c BN(Yk).
// De-serialized: norm phase uses all 256 threads (wave w covers channels
// w*16..+16); rn folded into the GEMM A-operand (no LDS rescale pass);
// vsum partials via 4-lane shuffle. grid (64 chunks, 8 batch), block 256.
// ---------------------------------------------------------------------------
__global__ __launch_bounds__(256) void kv_kernel(
    const float* __restrict__ Yk, const float* __restrict__ Vv,
    const float* __restrict__ stats, const float* __restrict__ gamma,
    const float* __restrict__ beta, float* __restrict__ KVp,
    float* __restrict__ vsum)
{
    const int chunk = blockIdx.x;       // 0..63, 64 cols
    const int b     = blockIdx.y;
    __shared__ float sk[64][68];
    __shared__ float sv[64][68];
    __shared__ float pn[4][64];         // per-wave norm partials
    __shared__ float rn[64];
    __shared__ float sscl[64], sshf[64];

    const int t = threadIdx.x;
    const int wave = t >> 6, lane = t & 63;
    if (t < 64) {
        float S  = stats[(64 + t) * 16];      // which = 1 (k)
        float SS = stats[(64 + t) * 16 + 4];
        float mean = S * (1.f / BN_COUNT);
        float var  = SS * (1.f / BN_COUNT) - mean * mean;
        float scl  = gamma[t] * rsqrtf(var + 1e-5f);
        sscl[t] = scl;
        sshf[t] = beta[t] - mean * scl;
    }
    __syncthreads();

    const int n0 = chunk * 64;
    const float* Ykb = Yk + (size_t)b * (CK * NTOT) + n0;
    const float* Vb  = Vv + (size_t)b * (CK * NTOT) + n0;

    // Stage: 64 c x 64 j for k (BN applied) and v
#pragma unroll
    for (int r = 0; r < 4; ++r) {
        int idx4 = t + r * 256;           // 0..1023
        int c  = idx4 >> 4;               // 0..63
        int j4 = (idx4 & 15) << 2;        // 0..60
        float4 kf = *(const float4*)(Ykb + (size_t)c * NTOT + j4);
        float4 vf = *(const float4*)(Vb  + (size_t)c * NTOT + j4);
        float scl = sscl[c], sh = sshf[c];
        float4 ks = make_float4(kf.x * scl + sh, kf.y * scl + sh,
                                kf.z * scl + sh, kf.w * scl + sh);
        *(float4*)&sk[c][j4] = ks;
        *(float4*)&sv[c][j4] = vf;
    }
    __syncthreads();

    // Parallel norm partials: wave w sums channels w*16..+16 for its lane-col
    {
        float s = 0.f;
#pragma unroll
        for (int i = 0; i < 16; ++i) { float x = sk[wave * 16 + i][lane]; s += x * x; }
        pn[wave][lane] = s;
    }
    // vsum partials: thread t covers channel t>>2, column quarter t&3
    {
        const int v = t >> 2, q = t & 3;
        float s = 0.f;
#pragma unroll
        for (int i = 0; i < 16; ++i) s += sv[v][q * 16 + i];
        s += __shfl_down(s, 2, 64);
        s += __shfl_down(s, 1, 64);
        if (q == 0) atomicAdd(&vsum[((size_t)b * 64 + v) * 16], s);
    }
    __syncthreads();
    if (t < 64)
        rn[t] = 1.f / (sqrtf(pn[0][t] + pn[1][t] + pn[2][t] + pn[3][t]) + 1e-7f);
    __syncthreads();

    // GEMM: acc[c4][v4] over 64 columns, rn folded into the A-operand
    const int tc = t >> 4, tv = t & 15;
    float acc[4][4];
#pragma unroll
    for (int i = 0; i < 4; ++i)
#pragma unroll
        for (int k2 = 0; k2 < 4; ++k2) acc[i][k2] = 0.f;

#pragma unroll 2
    for (int jq = 0; jq < 16; ++jq) {
        float4 rq = *(const float4*)&rn[jq * 4];
        float4 a4[4], b4[4];
#pragma unroll
        for (int i = 0; i < 4; ++i) {
            float4 k4 = *(const float4*)&sk[tc * 4 + i][jq * 4];
            a4[i] = make_float4(k4.x * rq.x, k4.y * rq.y, k4.z * rq.z, k4.w * rq.w);
        }
#pragma unroll
        for (int k2 = 0; k2 < 4; ++k2) b4[k2] = *(const float4*)&sv[tv * 4 + k2][jq * 4];
#pragma unroll
        for (int i = 0; i < 4; ++i)
#pragma unroll
            for (int k2 = 0; k2 < 4; ++k2) {
                acc[i][k2] += a4[i].x * b4[k2].x + a4[i].y * b4[k2].y
                            + a4[i].z * b4[k2].z + a4[i].w * b4[k2].w;
            }
    }

    // Deterministic, coalesced partial store: KVp[b][chunk][c][v]
    float* P = KVp + ((size_t)(b * 64 + chunk)) * 4096;
#pragma unroll
    for (int i = 0; i < 4; ++i) {
        float4 st = make_float4(acc[i][0], acc[i][1], acc[i][2], acc[i][3]);
        *(float4*)&P[(tc * 4 + i) * 64 + tv * 4] = st;
    }
}

// ---------------------------------------------------------------------------
// Kernel 4: reduce KVp over 64 chunks (v-half per block) + partial GEMM:
// Mp[b][half][c][o] = sum_{v in half} KV[b,c,v]*Ww[o,v]
// dp[b][half][o]    = (half==0 ? bw[o] : 0) + sum_{v in half} Ww[o,v]*vsum[b,v]
// grid (2 halves, 8 batch), block 256.
// ---------------------------------------------------------------------------
__global__ __launch_bounds__(256) void m_kernel(
    const float* __restrict__ KVp, const float* __restrict__ vsum,
    const float* __restrict__ Ww, const float* __restrict__ bw,
    float* __restrict__ Mp, float* __restrict__ dp)
{
    const int half = blockIdx.x;        // 0..1 (v range half*32..+32)
    const int b    = blockIdx.y;
    __shared__ float sKV[64][36];       // [c][v-in-half]
    __shared__ float sWw[128][36];      // [o][v-in-half]
    __shared__ float svs[32];
    const int t = threadIdx.x;

    // Stage Ww half: 128 o x 32 v = 1024 float4s
#pragma unroll
    for (int r = 0; r < 4; ++r) {
        int idx4 = t + r * 256;          // 0..1023
        int o  = idx4 >> 3;              // 0..127
        int v4 = (idx4 & 7) << 2;        // 0..28
        *(float4*)&sWw[o][v4] = *(const float4*)(Ww + (size_t)o * 64 + half * 32 + v4);
    }
    if (t < 32) svs[t] = vsum[((size_t)b * 64 + half * 32 + t) * 16];

    // Reduce KVp over 64 chunks: 64 c x 32 v = 512 float4s, 2 per thread
    const float* base = KVp + (size_t)b * 64 * 4096;
    const int c0  = t >> 3;              // 0..31
    const int vq0 = (t & 7) << 2;        // 0..28
    const size_t off0 = (size_t)c0 * 64 + half * 32 + vq0;
    const size_t off1 = (size_t)(c0 + 32) * 64 + half * 32 + vq0;
    float4 r0 = make_float4(0.f, 0.f, 0.f, 0.f);
    float4 r1 = make_float4(0.f, 0.f, 0.f, 0.f);
#pragma unroll 4
    for (int ch = 0; ch < 64; ++ch) {
        const float* pc = base + (size_t)ch * 4096;
        float4 x0 = *(const float4*)(pc + off0);
        float4 x1 = *(const float4*)(pc + off1);
        r0.x += x0.x; r0.y += x0.y; r0.z += x0.z; r0.w += x0.w;
        r1.x += x1.x; r1.y += x1.y; r1.z += x1.z; r1.w += x1.w;
    }
    *(float4*)&sKV[c0][vq0]      = r0;
    *(float4*)&sKV[c0 + 32][vq0] = r1;
    __syncthreads();

    // Partial M: thread owns c = t&63, o group = (t>>6)*32..+32
    const int c  = t & 63;
    const int og = (t >> 6) * 32;
    float kreg[32];
#pragma unroll
    for (int vq = 0; vq < 8; ++vq) {
        float4 kv4 = *(const float4*)&sKV[c][vq * 4];
        kreg[vq * 4 + 0] = kv4.x; kreg[vq * 4 + 1] = kv4.y;
        kreg[vq * 4 + 2] = kv4.z; kreg[vq * 4 + 3] = kv4.w;
    }
    float* Mpb = Mp + ((size_t)b * 2 + half) * 8192;
#pragma unroll
    for (int oi = 0; oi < 32; ++oi) {
        const int o = og + oi;
        float acc = 0.f;
#pragma unroll
        for (int vq = 0; vq < 8; ++vq) {
            float4 w4 = *(const float4*)&sWw[o][vq * 4];
            acc += kreg[vq * 4 + 0] * w4.x + kreg[vq * 4 + 1] * w4.y
                 + kreg[vq * 4 + 2] * w4.z + kreg[vq * 4 + 3] * w4.w;
        }
        Mpb[(size_t)c * CO + o] = acc;
    }

    // Partial d
    if (t < 128) {
        float acc = (half == 0) ? bw[t] : 0.f;
#pragma unroll 8
        for (int v = 0; v < 32; ++v) acc += sWw[t][v] * svs[v];
        dp[((size_t)b * 2 + half) * 128 + t] = acc;
    }
}

// ---------------------------------------------------------------------------
// Kernel 5: out[b,o,n] = d[b,o] + rn[n] * sum_c sq[b,c,n] * M[b,c,o]
// (rn factored out of the GEMM). Norm phase de-serialized across all 256
// threads. sM = Mp0+Mp1, sd = dp0+dp1. grid (64 chunks, 8 batch), block 256.
// ---------------------------------------------------------------------------
__global__ __launch_bounds__(256) void out_kernel(
    const float* __restrict__ Yq, const float* __restrict__ stats,
    const float* __restrict__ gamma, const float* __restrict__ beta,
    const float* __restrict__ Mp, const float* __restrict__ dp,
    float* __restrict__ out)
{
    const int chunk = blockIdx.x;
    const int b     = blockIdx.y;
    __shared__ float sM[CK * CO];    // [c][o] flat, 32 KB
    __shared__ float sq[64][68];     // padded, float4-aligned rows
    __shared__ float pn[4][64];
    __shared__ float rn[64];
    __shared__ float sd[CO];
    __shared__ float sscl[64], sshf[64];

    const int t = threadIdx.x;
    const int wave = t >> 6, lane = t & 63;
    const int n0 = chunk * 64;

    const float* Mp0 = Mp + (size_t)b * 2 * 8192;
    const float* Mp1 = Mp0 + 8192;
#pragma unroll
    for (int r = 0; r < 8; ++r) {
        int idx4 = t + r * 256;
        float4 m0 = ((const float4*)Mp0)[idx4];
        float4 m1 = ((const float4*)Mp1)[idx4];
        ((float4*)sM)[idx4] = make_float4(m0.x + m1.x, m0.y + m1.y,
                                          m0.z + m1.z, m0.w + m1.w);
    }
    if (t < CO) sd[t] = dp[(size_t)b * 2 * 128 + t] + dp[((size_t)b * 2 + 1) * 128 + t];
    if (t < 64) {
        float S  = stats[t * 16];            // which = 0 (q)
        float SS = stats[t * 16 + 4];
        float mean = S * (1.f / BN_COUNT);
        float var  = SS * (1.f / BN_COUNT) - mean * mean;
        float scl  = gamma[t] * rsqrtf(var + 1e-5f);
        sscl[t] = scl;
        sshf[t] = beta[t] - mean * scl;
    }
    __syncthreads();   // sscl/sshf ready before sq staging

    const float* Yb = Yq + (size_t)b * (CK * NTOT) + n0;
#pragma unroll
    for (int r = 0; r < 4; ++r) {
        int idx4 = t + r * 256;
        int c  = idx4 >> 4;
        int j4 = (idx4 & 15) << 2;
        float4 xv = *(const float4*)(Yb + (size_t)c * NTOT + j4);
        float scl = sscl[c], sh = sshf[c];
        sq[c][j4 + 0] = xv.x * scl + sh;
        sq[c][j4 + 1] = xv.y * scl + sh;
        sq[c][j4 + 2] = xv.z * scl + sh;
        sq[c][j4 + 3] = xv.w * scl + sh;
    }
    __syncthreads();

    // Parallel norm partials: wave w sums channels w*16..+16 for its lane-col
    {
        float s = 0.f;
#pragma unroll
        for (int i = 0; i < 16; ++i) { float x = sq[wave * 16 + i][lane]; s += x * x; }
        pn[wave][lane] = s;
    }
    __syncthreads();
    if (t < 64)
        rn[t] = 1.f / (sqrtf(pn[0][t] + pn[1][t] + pn[2][t] + pn[3][t]) + 1e-7f);
    __syncthreads();

    const int j0 = (t & 15) << 2;       // 4 columns
    const int o0 = (t >> 4) << 3;       // 8 out-channels
    float acc[4][8];
#pragma unroll
    for (int jj = 0; jj < 4; ++jj)
#pragma unroll
        for (int oo = 0; oo < 8; ++oo) acc[jj][oo] = 0.f;

#pragma unroll 4
    for (int c = 0; c < 64; ++c) {
        float4 qv = *(const float4*)&sq[c][j0];
        float4 m0 = *(const float4*)&sM[c * CO + o0];
        float4 m1 = *(const float4*)&sM[c * CO + o0 + 4];
        float aq[4] = {qv.x, qv.y, qv.z, qv.w};
        float am[8] = {m0.x, m0.y, m0.z, m0.w, m1.x, m1.y, m1.z, m1.w};
#pragma unroll
        for (int jj = 0; jj < 4; ++jj)
#pragma unroll
            for (int oo = 0; oo < 8; ++oo) acc[jj][oo] += aq[jj] * am[oo];
    }

    float4 rq = *(const float4*)&rn[j0];   // per-thread column norms
    float rnj[4] = {rq.x, rq.y, rq.z, rq.w};

    float* outb = out + (size_t)b * (CO * NTOT) + n0;
#pragma unroll
    for (int oo = 0; oo < 8; ++oo) {
        float dd = sd[o0 + oo];
        float4 st = make_float4(acc[0][oo] * rnj[0] + dd,
                                acc[1][oo] * rnj[1] + dd,
                                acc[2][oo] * rnj[2] + dd,
                                acc[3][oo] * rnj[3] + dd);
        *(float4*)&outb[(size_t)(o0 + oo) * NTOT + j0] = st;
    }
}

// ---------------------------------------------------------------------------
extern "C" void kernel_launch(void* const* d_in, const int* in_sizes, int n_in,
                              void* d_out, int out_size, void* d_ws, size_t ws_size,
                              hipStream_t stream) {
    (void)in_sizes; (void)n_in; (void)out_size; (void)ws_size;
    const float* q     = (const float*)d_in[0];
    const float* k     = (const float*)d_in[1];
    const float* v     = (const float*)d_in[2];
    const float* Wk    = (const float*)d_in[3];
    const float* bk    = (const float*)d_in[4];
    const float* gamma = (const float*)d_in[5];
    const float* beta  = (const float*)d_in[6];
    const float* Wv    = (const float*)d_in[7];
    const float* bv    = (const float*)d_in[8];
    const float* Ww    = (const float*)d_in[9];
    const float* bw    = (const float*)d_in[10];
    float* out = (float*)d_out;
    float* ws  = (float*)d_ws;

    float* Yq    = ws + OFF_YQ;
    float* Yk    = ws + OFF_YK;
    float* Vv    = ws + OFF_V;
    float* stats = ws + OFF_STATS;
    float* vsum  = ws + OFF_VSUM;
    float* Mp    = ws + OFF_MP;    // aliases dead Yk region (stream-ordered safe)
    float* dp    = ws + OFF_DP;    // aliases dead Yk region
    float* KVp   = out;            // d_out as scratch; fully overwritten by out_kernel

    // zero atomic-accumulated buffers (stats + vsum contiguous, 40 KB)
    hipMemsetAsync(stats, 0, (2048 + 8192) * sizeof(float), stream);

    gemm3_kernel<<<dim3(64, NBATCH, 3), 256, 0, stream>>>(
        q, k, v, Wk, bk, Wv, bv, Yq, Yk, Vv);
    stats_kernel<<<dim3(8, 64, 2), 256, 0, stream>>>(Yq, Yk, stats);
    kv_kernel<<<dim3(64, NBATCH), 256, 0, stream>>>(Yk, Vv, stats, gamma, beta, KVp, vsum);
    m_kernel<<<dim3(2, NBATCH), 256, 0, stream>>>(KVp, vsum, Ww, bw, Mp, dp);
    out_kernel<<<dim3(64, NBATCH), 256, 0, stream>>>(Yq, stats, gamma, beta, Mp, dp, out);
}

// Round 7
// 180.687 us; speedup vs baseline: 2.6958x; 1.0477x over previous
//
#include <hip/hip_runtime.h>
#include <math.h>

// Problem constants
#define NTOT 4096        // H*W = 64*64
#define NBATCH 8
#define CIN 128
#define CK 64
#define CV 64
#define CO 128
#define BN_COUNT 32768.0f // B*H*W

// Workspace layout (float offsets).
// stats: [(which*64+c)*16] sum, +4 sumsq  (line-exclusive per channel)
// vsum : [(b*64+v)*16]                    (line-exclusive per (b,v))
// M,d  : aliased into dead Yk region (Yk last read by kv_kernel; m_kernel after)
// KVp  : 64-chunk partials of KV in d_out scratch (overwritten by out_kernel)
#define OFF_YQ    0ul
#define OFF_YK    2097152ul
#define OFF_V     4194304ul
#define OFF_STATS 6291456ul           // 2*64*16 = 2048 floats
#define OFF_VSUM  6293504ul           // 8*64*16 = 8192 floats
#define OFF_M     2097152ul           // = OFF_YK, [b][64][128] = 65536 floats
#define OFF_D     2162688ul           // [b][128] = 1024 floats

// ---------------------------------------------------------------------------
// Kernel 1: LDS-staged 1x1-conv GEMM (round-0 proven: ~57us, VALU ~39%).
// grid (64 col-chunks, 8 batch, 3 tensors), block 256.
// ---------------------------------------------------------------------------
__global__ __launch_bounds__(256) void gemm3_kernel(
    const float* __restrict__ Xq, const float* __restrict__ Xk, const float* __restrict__ Xv,
    const float* __restrict__ Wk, const float* __restrict__ bk,
    const float* __restrict__ Wv, const float* __restrict__ bv,
    float* __restrict__ Yq, float* __restrict__ Yk, float* __restrict__ Vv)
{
    const int chunk = blockIdx.x;
    const int b     = blockIdx.y;
    const int which = blockIdx.z;
    const float* X    = (which == 0) ? Xq : (which == 1) ? Xk : Xv;
    const float* W    = (which == 2) ? Wv : Wk;
    const float* bias = (which == 2) ? bv : bk;
    float* Y          = (which == 0) ? Yq : (which == 1) ? Yk : Vv;

    __shared__ float sX[CIN][64];   // 32 KB

    const int t = threadIdx.x;
    const int lane = t & 63;
    const int wu = __builtin_amdgcn_readfirstlane(t >> 6);  // wave id, uniform

    const int n0 = chunk * 64;
    const float* Xb = X + (size_t)b * (CIN * NTOT) + n0;

#pragma unroll
    for (int r = 0; r < 8; ++r) {
        int idx4 = t + r * 256;           // 0..2047
        int c  = idx4 >> 4;               // 0..127
        int j4 = (idx4 & 15) << 2;        // 0..60
        float4 xv = *(const float4*)(Xb + (size_t)c * NTOT + j4);
        *(float4*)&sX[c][j4] = xv;
    }
    __syncthreads();

    const float* Wp = W + (size_t)wu * 16 * CIN;
    float acc[16];
#pragma unroll
    for (int ki = 0; ki < 16; ++ki) acc[ki] = 0.f;

#pragma unroll 8
    for (int c = 0; c < CIN; ++c) {
        float xv = sX[c][lane];
#pragma unroll
        for (int ki = 0; ki < 16; ++ki)
            acc[ki] += xv * Wp[ki * CIN + c];   // wave-uniform -> s_load
    }

    float* Yb = Y + (size_t)b * (CK * NTOT) + n0;
#pragma unroll
    for (int ki = 0; ki < 16; ++ki) {
        int o = wu * 16 + ki;
        Yb[(size_t)o * NTOT + lane] = acc[ki] + bias[o];
    }
}

// ---------------------------------------------------------------------------
// Kernel 2: BN batch stats. grid (8 n-splits, 64 c, 2 tensors) = 1024 blocks;
// 16KB coalesced per block, block-reduce, 2 padded atomics (16 ops/line).
// ---------------------------------------------------------------------------
__global__ __launch_bounds__(256) void stats_kernel(
    const float* __restrict__ Yq, const float* __restrict__ Yk,
    float* __restrict__ stats)
{
    const int nsplit = blockIdx.x;   // 0..7
    const int c      = blockIdx.y;   // 0..63
    const int which  = blockIdx.z;   // 0..1
    const float* Y = which ? Yk : Yq;
    const int t = threadIdx.x;

    float s = 0.f, ss = 0.f;
#pragma unroll
    for (int p = 0; p < 4; ++p) {
        int b = (t >> 7) + p * 2;        // 2 batches per pass
        int e = (t & 127) << 2;          // 0..508
        const float* src = Y + (size_t)b * (CK * NTOT) + (size_t)c * NTOT
                         + nsplit * 512 + e;
        float4 v = *(const float4*)src;
        s  += v.x + v.y + v.z + v.w;
        ss += v.x * v.x + v.y * v.y + v.z * v.z + v.w * v.w;
    }
#pragma unroll
    for (int off = 32; off > 0; off >>= 1) {
        s  += __shfl_down(s, off, 64);
        ss += __shfl_down(ss, off, 64);
    }
    __shared__ float red[8];
    int wave = t >> 6, lane = t & 63;
    if (lane == 0) { red[wave * 2] = s; red[wave * 2 + 1] = ss; }
    __syncthreads();
    if (t == 0) {
        float S  = red[0] + red[2] + red[4] + red[6];
        float SS = red[1] + red[3] + red[5] + red[7];
        atomicAdd(&stats[(which * 64 + c) * 16],     S);
        atomicAdd(&stats[(which * 64 + c) * 16 + 4], SS);
    }
}

// ---------------------------------------------------------------------------
// Kernel 3: KV partials (atomic-free into d_out scratch) + vsum (padded
// atomics). kn = L2-normalized-over-c BN(Yk). UNCHANGED from round 6
// (control for the out_kernel block-count experiment).
// grid (64 chunks, 8 batch), block 256.
// ---------------------------------------------------------------------------
__global__ __launch_bounds__(256) void kv_kernel(
    const float* __restrict__ Yk, const float* __restrict__ Vv,
    const float* __restrict__ stats, const float* __restrict__ gamma,
    const float* __restrict__ beta, float* __restrict__ KVp,
    float* __restrict__ vsum)
{
    const int chunk = blockIdx.x;       // 0..63, 64 cols
    const int b     = blockIdx.y;
    __shared__ float sk[64][68];
    __shared__ float sv[64][68];
    __shared__ float pn[4][64];         // per-wave norm partials
    __shared__ float rn[64];
    __shared__ float sscl[64], sshf[64];

    const int t = threadIdx.x;
    const int wave = t >> 6, lane = t & 63;
    if (t < 64) {
        float S  = stats[(64 + t) * 16];      // which = 1 (k)
        float SS = stats[(64 + t) * 16 + 4];
        float mean = S * (1.f / BN_COUNT);
        float var  = SS * (1.f / BN_COUNT) - mean * mean;
        float scl  = gamma[t] * rsqrtf(var + 1e-5f);
        sscl[t] = scl;
        sshf[t] = beta[t] - mean * scl;
    }
    __syncthreads();

    const int n0 = chunk * 64;
    const float* Ykb = Yk + (size_t)b * (CK * NTOT) + n0;
    const float* Vb  = Vv + (size_t)b * (CK * NTOT) + n0;

#pragma unroll
    for (int r = 0; r < 4; ++r) {
        int idx4 = t + r * 256;           // 0..1023
        int c  = idx4 >> 4;               // 0..63
        int j4 = (idx4 & 15) << 2;        // 0..60
        float4 kf = *(const float4*)(Ykb + (size_t)c * NTOT + j4);
        float4 vf = *(const float4*)(Vb  + (size_t)c * NTOT + j4);
        float scl = sscl[c], sh = sshf[c];
        float4 ks = make_float4(kf.x * scl + sh, kf.y * scl + sh,
                                kf.z * scl + sh, kf.w * scl + sh);
        *(float4*)&sk[c][j4] = ks;
        *(float4*)&sv[c][j4] = vf;
    }
    __syncthreads();

    // Parallel norm partials: wave w sums channels w*16..+16 for its lane-col
    {
        float s = 0.f;
#pragma unroll
        for (int i = 0; i < 16; ++i) { float x = sk[wave * 16 + i][lane]; s += x * x; }
        pn[wave][lane] = s;
    }
    // vsum partials: thread t covers channel t>>2, column quarter t&3
    {
        const int v = t >> 2, q = t & 3;
        float s = 0.f;
#pragma unroll
        for (int i = 0; i < 16; ++i) s += sv[v][q * 16 + i];
        s += __shfl_down(s, 2, 64);
        s += __shfl_down(s, 1, 64);
        if (q == 0) atomicAdd(&vsum[((size_t)b * 64 + v) * 16], s);
    }
    __syncthreads();
    if (t < 64)
        rn[t] = 1.f / (sqrtf(pn[0][t] + pn[1][t] + pn[2][t] + pn[3][t]) + 1e-7f);
    __syncthreads();

    // GEMM: acc[c4][v4] over 64 columns, rn folded into the A-operand
    const int tc = t >> 4, tv = t & 15;
    float acc[4][4];
#pragma unroll
    for (int i = 0; i < 4; ++i)
#pragma unroll
        for (int k2 = 0; k2 < 4; ++k2) acc[i][k2] = 0.f;

#pragma unroll 2
    for (int jq = 0; jq < 16; ++jq) {
        float4 rq = *(const float4*)&rn[jq * 4];
        float4 a4[4], b4[4];
#pragma unroll
        for (int i = 0; i < 4; ++i) {
            float4 k4 = *(const float4*)&sk[tc * 4 + i][jq * 4];
            a4[i] = make_float4(k4.x * rq.x, k4.y * rq.y, k4.z * rq.z, k4.w * rq.w);
        }
#pragma unroll
        for (int k2 = 0; k2 < 4; ++k2) b4[k2] = *(const float4*)&sv[tv * 4 + k2][jq * 4];
#pragma unroll
        for (int i = 0; i < 4; ++i)
#pragma unroll
            for (int k2 = 0; k2 < 4; ++k2) {
                acc[i][k2] += a4[i].x * b4[k2].x + a4[i].y * b4[k2].y
                            + a4[i].z * b4[k2].z + a4[i].w * b4[k2].w;
            }
    }

    // Deterministic, coalesced partial store: KVp[b][chunk][c][v]
    float* P = KVp + ((size_t)(b * 64 + chunk)) * 4096;
#pragma unroll
    for (int i = 0; i < 4; ++i) {
        float4 st = make_float4(acc[i][0], acc[i][1], acc[i][2], acc[i][3]);
        *(float4*)&P[(tc * 4 + i) * 64 + tv * 4] = st;
    }
}

// ---------------------------------------------------------------------------
// Kernel 4: fused reduce+GEMM. Round-6 lesson: old m_kernel read 8.4 MB KVp
// with 16 blocks (BW-starved, strided halves) -> est. 15-25us. Now: grid
// (16 c-slices, 8 b) = 128 blocks; each reduces its 4 c-rows over 64 chunks
// (full-width 256B segments) and computes those 4 M rows directly
// (M row c depends only on KV row c). dp folded into slice-0 blocks.
// ---------------------------------------------------------------------------
__global__ __launch_bounds__(256) void m_kernel(
    const float* __restrict__ KVp, const float* __restrict__ vsum,
    const float* __restrict__ Ww, const float* __restrict__ bw,
    float* __restrict__ M, float* __restrict__ d)
{
    const int slice = blockIdx.x;       // 0..15 -> c rows slice*4..+4
    const int b     = blockIdx.y;
    __shared__ float part[256][4];      // per-thread float4 partials
    __shared__ float sKV[4][68];        // reduced slice rows
    __shared__ float sWw[128][68];      // full Ww, padded rows
    __shared__ float svs[64];
    const int t = threadIdx.x;

    // Stage full Ww: 128 o x 64 v = 2048 float4s, 8 per thread
#pragma unroll
    for (int r = 0; r < 8; ++r) {
        int idx4 = t + r * 256;          // 0..2047
        int o  = idx4 >> 4;              // 0..127
        int v4 = (idx4 & 15) << 2;       // 0..60
        *(float4*)&sWw[o][v4] = *(const float4*)(Ww + (size_t)o * 64 + v4);
    }
    if (t < 64) svs[t] = vsum[((size_t)b * 64 + t) * 16];

    // Reduce KVp over 64 chunks for this 4-row slice (each chunk-slice = 1KB,
    // read as 4 ch in parallel across the block's 4 chl groups).
    const int chl = t >> 6;              // 0..3
    const int ci  = (t >> 4) & 3;        // 0..3  (c within slice)
    const int v4  = (t & 15) << 2;       // 0..60
    const size_t rowoff = ((size_t)(slice * 4 + ci)) * 64 + v4;
    float4 a4 = make_float4(0.f, 0.f, 0.f, 0.f);
#pragma unroll 4
    for (int it = 0; it < 16; ++it) {
        int ch = it * 4 + chl;
        float4 x = *(const float4*)(KVp + ((size_t)(b * 64 + ch)) * 4096 + rowoff);
        a4.x += x.x; a4.y += x.y; a4.z += x.z; a4.w += x.w;
    }
    *(float4*)&part[t][0] = a4;
    __syncthreads();
    if (t < 64) {
        float4 p0 = *(const float4*)&part[t][0];
        float4 p1 = *(const float4*)&part[t + 64][0];
        float4 p2 = *(const float4*)&part[t + 128][0];
        float4 p3 = *(const float4*)&part[t + 192][0];
        *(float4*)&sKV[(t >> 4) & 3][(t & 15) << 2] =
            make_float4(p0.x + p1.x + p2.x + p3.x, p0.y + p1.y + p2.y + p3.y,
                        p0.z + p1.z + p2.z + p3.z, p0.w + p1.w + p2.w + p3.w);
    }
    __syncthreads();

    // GEMM: 4 c x 128 o = 512 outputs, 2 per thread
    float* Mb = M + (size_t)b * (CK * CO);
#pragma unroll
    for (int rep = 0; rep < 2; ++rep) {
        int idx = t + rep * 256;         // 0..511
        int c = idx >> 7, o = idx & 127;
        float acc = 0.f;
#pragma unroll
        for (int vq = 0; vq < 16; ++vq) {
            float4 kv4 = *(const float4*)&sKV[c][vq * 4];
            float4 w4  = *(const float4*)&sWw[o][vq * 4];
            acc += kv4.x * w4.x + kv4.y * w4.y + kv4.z * w4.z + kv4.w * w4.w;
        }
        Mb[(size_t)(slice * 4 + c) * CO + o] = acc;
    }

    // d: only slice-0 blocks
    if (slice == 0 && t < 128) {
        float acc = bw[t];
#pragma unroll 16
        for (int v = 0; v < 64; ++v) acc += sWw[t][v] * svs[v];
        d[(size_t)b * CO + t] = acc;
    }
}

// ---------------------------------------------------------------------------
// Kernel 5: out[b,o,n] = d[b,o] + rn[n] * sum_c sq[b,c,n] * M[b,c,o].
// 32-col chunks -> grid (128, 8) = 1024 blocks (~4/CU) to overlap the
// barrier-chained stage->norm->GEMM phases across more resident blocks
// (round-6 falsifier: serial-norm wasn't the cost; testing block-starvation).
// ---------------------------------------------------------------------------
__global__ __launch_bounds__(256) void out_kernel(
    const float* __restrict__ Yq, const float* __restrict__ stats,
    const float* __restrict__ gamma, const float* __restrict__ beta,
    const float* __restrict__ M, const float* __restrict__ d,
    float* __restrict__ out)
{
    const int chunk = blockIdx.x;    // 0..127, 32 cols
    const int b     = blockIdx.y;
    __shared__ float sM[CK * CO];    // [c][o] flat, 32 KB
    __shared__ float sq[64][36];     // 32 cols + pad (rows 144B, 16B-aligned)
    __shared__ float pn[8][32];
    __shared__ float rn[32];
    __shared__ float sd[CO];
    __shared__ float sscl[64], sshf[64];

    const int t = threadIdx.x;
    const int n0 = chunk * 32;

#pragma unroll
    for (int r = 0; r < 8; ++r) {
        int idx4 = t + r * 256;
        ((float4*)sM)[idx4] = ((const float4*)(M + (size_t)b * (CK * CO)))[idx4];
    }
    if (t < CO) sd[t] = d[(size_t)b * CO + t];
    if (t < 64) {
        float S  = stats[t * 16];            // which = 0 (q)
        float SS = stats[t * 16 + 4];
        float mean = S * (1.f / BN_COUNT);
        float var  = SS * (1.f / BN_COUNT) - mean * mean;
        float scl  = gamma[t] * rsqrtf(var + 1e-5f);
        sscl[t] = scl;
        sshf[t] = beta[t] - mean * scl;
    }
    __syncthreads();   // sscl/sshf ready before sq staging

    const float* Yb = Yq + (size_t)b * (CK * NTOT) + n0;
#pragma unroll
    for (int r = 0; r < 2; ++r) {
        int idx4 = t + r * 256;        // 0..511
        int c  = idx4 >> 3;            // 0..63
        int j4 = (idx4 & 7) << 2;      // 0..28
        float4 xv = *(const float4*)(Yb + (size_t)c * NTOT + j4);
        float scl = sscl[c], sh = sshf[c];
        sq[c][j4 + 0] = xv.x * scl + sh;
        sq[c][j4 + 1] = xv.y * scl + sh;
        sq[c][j4 + 2] = xv.z * scl + sh;
        sq[c][j4 + 3] = xv.w * scl + sh;
    }
    __syncthreads();

    // Parallel norm partials: group g (of 8) sums channels g*8..+8 per col
    {
        const int col = t & 31, g = t >> 5;
        float s = 0.f;
#pragma unroll
        for (int i = 0; i < 8; ++i) { float x = sq[g * 8 + i][col]; s += x * x; }
        pn[g][col] = s;
    }
    __syncthreads();
    if (t < 32) {
        float s2 = pn[0][t] + pn[1][t] + pn[2][t] + pn[3][t]
                 + pn[4][t] + pn[5][t] + pn[6][t] + pn[7][t];
        rn[t] = 1.f / (sqrtf(s2) + 1e-7f);
    }
    __syncthreads();

    const int j0 = (t & 7) << 2;        // 4 columns
    const int o0 = (t >> 3) << 2;       // 4 out-channels
    float acc[4][4];
#pragma unroll
    for (int jj = 0; jj < 4; ++jj)
#pragma unroll
        for (int oo = 0; oo < 4; ++oo) acc[jj][oo] = 0.f;

#pragma unroll 4
    for (int c = 0; c < 64; ++c) {
        float4 qv = *(const float4*)&sq[c][j0];
        float4 m0 = *(const float4*)&sM[c * CO + o0];
        float aq[4] = {qv.x, qv.y, qv.z, qv.w};
        float am[4] = {m0.x, m0.y, m0.z, m0.w};
#pragma unroll
        for (int jj = 0; jj < 4; ++jj)
#pragma unroll
            for (int oo = 0; oo < 4; ++oo) acc[jj][oo] += aq[jj] * am[oo];
    }

    float4 rq = *(const float4*)&rn[j0];   // per-thread column norms

    float* outb = out + (size_t)b * (CO * NTOT) + n0;
#pragma unroll
    for (int oo = 0; oo < 4; ++oo) {
        float dd = sd[o0 + oo];
        float4 st = make_float4(acc[0][oo] * rq.x + dd,
                                acc[1][oo] * rq.y + dd,
                                acc[2][oo] * rq.z + dd,
                                acc[3][oo] * rq.w + dd);
        *(float4*)&outb[(size_t)(o0 + oo) * NTOT + j0] = st;
    }
}

// ---------------------------------------------------------------------------
extern "C" void kernel_launch(void* const* d_in, const int* in_sizes, int n_in,
                              void* d_out, int out_size, void* d_ws, size_t ws_size,
                              hipStream_t stream) {
    (void)in_sizes; (void)n_in; (void)out_size; (void)ws_size;
    const float* q     = (const float*)d_in[0];
    const float* k     = (const float*)d_in[1];
    const float* v     = (const float*)d_in[2];
    const float* Wk    = (const float*)d_in[3];
    const float* bk    = (const float*)d_in[4];
    const float* gamma = (const float*)d_in[5];
    const float* beta  = (const float*)d_in[6];
    const float* Wv    = (const float*)d_in[7];
    const float* bv    = (const float*)d_in[8];
    const float* Ww    = (const float*)d_in[9];
    const float* bw    = (const float*)d_in[10];
    float* out = (float*)d_out;
    float* ws  = (float*)d_ws;

    float* Yq    = ws + OFF_YQ;
    float* Yk    = ws + OFF_YK;
    float* Vv    = ws + OFF_V;
    float* stats = ws + OFF_STATS;
    float* vsum  = ws + OFF_VSUM;
    float* M     = ws + OFF_M;     // aliases dead Yk region (stream-ordered safe)
    float* dd    = ws + OFF_D;     // aliases dead Yk region
    float* KVp   = out;            // d_out as scratch; fully overwritten by out_kernel

    // zero atomic-accumulated buffers (stats + vsum contiguous, 40 KB)
    hipMemsetAsync(stats, 0, (2048 + 8192) * sizeof(float), stream);

    gemm3_kernel<<<dim3(64, NBATCH, 3), 256, 0, stream>>>(
        q, k, v, Wk, bk, Wv, bv, Yq, Yk, Vv);
    stats_kernel<<<dim3(8, 64, 2), 256, 0, stream>>>(Yq, Yk, stats);
    kv_kernel<<<dim3(64, NBATCH), 256, 0, stream>>>(Yk, Vv, stats, gamma, beta, KVp, vsum);
    m_kernel<<<dim3(16, NBATCH), 256, 0, stream>>>(KVp, vsum, Ww, bw, M, dd);
    out_kernel<<<dim3(128, NBATCH), 256, 0, stream>>>(Yq, stats, gamma, beta, M, dd, out);
}